// Round 6
// baseline (387.527 us; speedup 1.0000x reference)
//
#include <hip/hip_runtime.h>
#include <hip/hip_bf16.h>
#include <math.h>

#define NN 65536
#define EE 1048576
#define NG 512

// k_pre block split: link | pack | gbound
#define LINK_B 1024       // EE/4/256 exactly
#define PACK_B 26
#define GB_B   3
#define PRE_B  (LINK_B + PACK_B + GB_B)
#define POOL_B 512

typedef __attribute__((ext_vector_type(8))) short bf16x8;
typedef __attribute__((ext_vector_type(4))) float f32x4;

__device__ __constant__ const float BNS = 0.9999950000374997f; // 1/sqrt(1+1e-5)

// ---------------- bf16 helpers ----------------
__device__ inline float lo_bf(uint u) { union { uint i; float f; } v; v.i = u << 16; return v.f; }
__device__ inline float hi_bf(uint u) { union { uint i; float f; } v; v.i = u & 0xFFFF0000u; return v.f; }
__device__ inline uint f2bf(float f) {
  union { float f; uint i; } v; v.f = f;
  uint r = v.i + 0x7FFFu + ((v.i >> 16) & 1u);  // RTNE
  return r >> 16;
}
__device__ inline uint pack_bf2(float a, float b) { return f2bf(a) | (f2bf(b) << 16); }
__device__ inline void cvt8(uint4 v, float* o) {
  o[0] = lo_bf(v.x); o[1] = hi_bf(v.x); o[2] = lo_bf(v.y); o[3] = hi_bf(v.y);
  o[4] = lo_bf(v.z); o[5] = hi_bf(v.z); o[6] = lo_bf(v.w); o[7] = hi_bf(v.w);
}

// ================= device bodies =================

// per-dst linked list: nxt[e] = old head[dst[e]]. nxt stores are contiguous;
// only the atomicExch goes to a random (L2-resident, 256KB) location.
__device__ void dev_link(int lb, const int* __restrict__ ei,
                         int* __restrict__ head, int* __restrict__ nxt) {
  int i0 = (lb * 256 + threadIdx.x) * 4;
  int4 d4 = *(const int4*)(ei + EE + i0);
  int4 nv;
  nv.x = atomicExch(&head[d4.x], i0 + 0);
  nv.y = atomicExch(&head[d4.y], i0 + 1);
  nv.z = atomicExch(&head[d4.z], i0 + 2);
  nv.w = atomicExch(&head[d4.w], i0 + 3);
  *(int4*)(nxt + i0) = nv;
}

__device__ void dev_pack(int b,
    const float* __restrict__ Wl1, const float* __restrict__ Wr1,
    const float* __restrict__ Wl2, const float* __restrict__ Wr2,
    const float* __restrict__ Wl3, const float* __restrict__ Wr3,
    ushort* __restrict__ P1l, ushort* __restrict__ P1r,
    ushort* __restrict__ P2l, ushort* __restrict__ P2r,
    ushort* __restrict__ P3l, ushort* __restrict__ P3r) {
  const float* W; ushort* P; int FIN, FOUT, base;
  if (b < 8)       { W = Wl1; P = P1l; FIN = 128; FOUT = 128; base = b; }
  else if (b < 16) { W = Wr1; P = P1r; FIN = 128; FOUT = 128; base = b - 8; }
  else if (b < 20) { W = Wl2; P = P2l; FIN = 128; FOUT = 64;  base = b - 16; }
  else if (b < 24) { W = Wr2; P = P2r; FIN = 128; FOUT = 64;  base = b - 20; }
  else if (b < 25) { W = Wl3; P = P3l; FIN = 64;  FOUT = 32;  base = 0; }
  else             { W = Wr3; P = P3r; FIN = 64;  FOUT = 32;  base = 0; }
  int tid = base * 256 + threadIdx.x;
  int KS = FIN / 32, NF = FOUT / 16;
  if (tid >= NF * KS * 64) return;
  int lane = tid & 63, t = (tid >> 6) % KS, cf = (tid >> 6) / KS;
  int f = cf * 16 + (lane & 15);
  int k0 = t * 32 + (lane >> 4) * 8;
  uint4 v;
  v.x = pack_bf2(W[(k0 + 0) * FOUT + f], W[(k0 + 1) * FOUT + f]);
  v.y = pack_bf2(W[(k0 + 2) * FOUT + f], W[(k0 + 3) * FOUT + f]);
  v.z = pack_bf2(W[(k0 + 4) * FOUT + f], W[(k0 + 5) * FOUT + f]);
  v.w = pack_bf2(W[(k0 + 6) * FOUT + f], W[(k0 + 7) * FOUT + f]);
  ((uint4*)P)[tid] = v;
}

__device__ void dev_gbound(int lb, const int* __restrict__ batch,
                           int* __restrict__ goff) {
  int g = lb * 256 + threadIdx.x;
  if (g > NG) return;
  int lo = 0, hi = NN;
  while (lo < hi) {
    int mid = (lo + hi) >> 1;
    if (batch[mid] < g) lo = mid + 1; else hi = mid;
  }
  goff[g] = lo;
}

// bf16-input GEMM tile body (layers 2,3)
template <int FIN, int FOUT, int TILES>
__device__ void dev_gemm(int lb, const ushort* __restrict__ xin,
                         const ushort* __restrict__ Wlp,
                         const ushort* __restrict__ Wrp,
                         ushort* __restrict__ xl, ushort* __restrict__ xr) {
  constexpr int KS = FIN / 32;
  constexpr int NF = FOUT / 16;
  constexpr int FW = (NF < 4) ? NF : 4;
  constexpr int CFW = NF / FW;
  constexpr int NW = 4 / FW;
  const int w = threadIdx.x >> 6, lane = threadIdx.x & 63;
  const int fseg = w % FW, ng = w / FW;
  const int l15 = lane & 15, lhi = lane >> 4;

  bf16x8 wfl[CFW][KS], wfr[CFW][KS];
#pragma unroll
  for (int c = 0; c < CFW; ++c)
#pragma unroll
    for (int t = 0; t < KS; ++t) {
      int idx = ((fseg * CFW + c) * KS + t) * 64 + lane;
      wfl[c][t] = ((const bf16x8*)Wlp)[idx];
      wfr[c][t] = ((const bf16x8*)Wrp)[idx];
    }

  size_t tile0 = ((size_t)lb * NW + ng) * TILES;
  for (int it = 0; it < TILES; ++it) {
    int mb = (int)(tile0 + it) * 16;
    const bf16x8* xrow = (const bf16x8*)(xin + (size_t)(mb + l15) * FIN);
    bf16x8 bx[KS];
#pragma unroll
    for (int t = 0; t < KS; ++t) bx[t] = xrow[t * 4 + lhi];
    f32x4 accl[CFW], accr[CFW];
#pragma unroll
    for (int c = 0; c < CFW; ++c) {
      accl[c] = (f32x4){0.f, 0.f, 0.f, 0.f};
      accr[c] = (f32x4){0.f, 0.f, 0.f, 0.f};
    }
#pragma unroll
    for (int t = 0; t < KS; ++t)
#pragma unroll
      for (int c = 0; c < CFW; ++c) {
        accl[c] = __builtin_amdgcn_mfma_f32_16x16x32_bf16(wfl[c][t], bx[t], accl[c], 0, 0, 0);
        accr[c] = __builtin_amdgcn_mfma_f32_16x16x32_bf16(wfr[c][t], bx[t], accr[c], 0, 0, 0);
      }
#pragma unroll
    for (int c = 0; c < CFW; ++c) {
      int f0 = (fseg * CFW + c) * 16 + lhi * 4;
      size_t o = (size_t)(mb + l15) * FOUT + f0;
      uint2 vl; vl.x = pack_bf2(accl[c][0], accl[c][1]); vl.y = pack_bf2(accl[c][2], accl[c][3]);
      *(uint2*)(xl + o) = vl;
      uint2 vr; vr.x = pack_bf2(accr[c][0], accr[c][1]); vr.y = pack_bf2(accr[c][2], accr[c][3]);
      *(uint2*)(xr + o) = vr;
    }
  }
}

template <int FOUT>
__device__ void dev_pool(int g, const ushort* __restrict__ h,
                         const int* __restrict__ goff,
                         float* __restrict__ pooled, int colbase, int colbase2) {
  int t = threadIdx.x;
  constexpr int PAIRS = FOUT / 2;
  if (t >= PAIRS) return;
  float a0 = 0.f, a1 = 0.f;
  int b0 = goff[g], b1 = goff[g + 1];
  const uint* h32 = (const uint*)h;
  for (int n = b0; n < b1; ++n) {
    uint v = h32[(size_t)n * PAIRS + t];
    a0 += lo_bf(v);
    a1 += hi_bf(v);
  }
  pooled[g * 256 + colbase + 2 * t] = a0;
  pooled[g * 256 + colbase + 2 * t + 1] = a1;
  if (colbase2 >= 0) {
    pooled[g * 256 + colbase2 + 2 * t] = a0;
    pooled[g * 256 + colbase2 + 2 * t + 1] = a1;
  }
}

// ================= fused / standalone kernels =================

__global__ __launch_bounds__(256) void k_pre(
    const int* __restrict__ ei, int* __restrict__ head, int* __restrict__ nxt,
    const float* __restrict__ Wl1, const float* __restrict__ Wr1,
    const float* __restrict__ Wl2, const float* __restrict__ Wr2,
    const float* __restrict__ Wl3, const float* __restrict__ Wr3,
    ushort* __restrict__ P1l, ushort* __restrict__ P1r,
    ushort* __restrict__ P2l, ushort* __restrict__ P2r,
    ushort* __restrict__ P3l, ushort* __restrict__ P3r,
    const int* __restrict__ batch, int* __restrict__ goff) {
  int b = blockIdx.x;
  if (b < LINK_B) dev_link(b, ei, head, nxt);
  else if (b < LINK_B + PACK_B)
    dev_pack(b - LINK_B, Wl1, Wr1, Wl2, Wr2, Wl3, Wr3,
             P1l, P1r, P2l, P2r, P3l, P3r);
  else dev_gbound(b - LINK_B - PACK_B, batch, goff);
}

// layer-1 GEMM reading f32 x directly (in-register bf16 pack)
__global__ __launch_bounds__(256) void k_gemm1f(
    const float* __restrict__ x, const ushort* __restrict__ Wlp,
    const ushort* __restrict__ Wrp, ushort* __restrict__ xl,
    ushort* __restrict__ xr) {
  constexpr int KS = 4, CFW = 2;
  const int w = threadIdx.x >> 6, lane = threadIdx.x & 63;
  const int fseg = w;                 // 4 waves cover F=128
  const int l15 = lane & 15, lhi = lane >> 4;

  bf16x8 wfl[CFW][KS], wfr[CFW][KS];
#pragma unroll
  for (int c = 0; c < CFW; ++c)
#pragma unroll
    for (int t = 0; t < KS; ++t) {
      int idx = ((fseg * CFW + c) * KS + t) * 64 + lane;
      wfl[c][t] = ((const bf16x8*)Wlp)[idx];
      wfr[c][t] = ((const bf16x8*)Wrp)[idx];
    }

  for (int it = 0; it < 8; ++it) {
    int mb = (blockIdx.x * 8 + it) * 16;
    const float* xrow = x + (size_t)(mb + l15) * 128;
    bf16x8 bx[KS];
#pragma unroll
    for (int t = 0; t < KS; ++t) {
      float4 a0 = *(const float4*)(xrow + t * 32 + lhi * 8);
      float4 a1 = *(const float4*)(xrow + t * 32 + lhi * 8 + 4);
      uint4 u;
      u.x = pack_bf2(a0.x, a0.y); u.y = pack_bf2(a0.z, a0.w);
      u.z = pack_bf2(a1.x, a1.y); u.w = pack_bf2(a1.z, a1.w);
      bx[t] = *(bf16x8*)&u;
    }
    f32x4 accl[CFW], accr[CFW];
#pragma unroll
    for (int c = 0; c < CFW; ++c) {
      accl[c] = (f32x4){0.f, 0.f, 0.f, 0.f};
      accr[c] = (f32x4){0.f, 0.f, 0.f, 0.f};
    }
#pragma unroll
    for (int t = 0; t < KS; ++t)
#pragma unroll
      for (int c = 0; c < CFW; ++c) {
        accl[c] = __builtin_amdgcn_mfma_f32_16x16x32_bf16(wfl[c][t], bx[t], accl[c], 0, 0, 0);
        accr[c] = __builtin_amdgcn_mfma_f32_16x16x32_bf16(wfr[c][t], bx[t], accr[c], 0, 0, 0);
      }
#pragma unroll
    for (int c = 0; c < CFW; ++c) {
      int f0 = (fseg * CFW + c) * 16 + lhi * 4;
      size_t o = (size_t)(mb + l15) * 128 + f0;
      uint2 vl; vl.x = pack_bf2(accl[c][0], accl[c][1]); vl.y = pack_bf2(accl[c][2], accl[c][3]);
      *(uint2*)(xl + o) = vl;
      uint2 vr; vr.x = pack_bf2(accr[c][0], accr[c][1]); vr.y = pack_bf2(accr[c][2], accr[c][3]);
      *(uint2*)(xr + o) = vr;
    }
  }
}

__global__ __launch_bounds__(256) void k_pool1_gemm2(
    const ushort* __restrict__ h, const int* __restrict__ goff,
    float* __restrict__ pooled, const ushort* __restrict__ P2l,
    const ushort* __restrict__ P2r, ushort* __restrict__ xl,
    ushort* __restrict__ xr) {
  int b = blockIdx.x;
  if (b < POOL_B) dev_pool<128>(b, h, goff, pooled, 0, -1);
  else dev_gemm<128, 64, 8>(b - POOL_B, h, P2l, P2r, xl, xr);
}

__global__ __launch_bounds__(256) void k_pool2_gemm3(
    const ushort* __restrict__ h, const int* __restrict__ goff,
    float* __restrict__ pooled, const ushort* __restrict__ P3l,
    const ushort* __restrict__ P3r, ushort* __restrict__ xl,
    ushort* __restrict__ xr) {
  int b = blockIdx.x;
  if (b < POOL_B) dev_pool<64>(b, h, goff, pooled, 128, -1);
  else dev_gemm<64, 32, 8>(b - POOL_B, h, P3l, P3r, xl, xr);
}

// ================= edge aggregation: linked-list walk, online softmax ========

template <int FOUT>
__global__ __launch_bounds__(256) void edge_kernel(
    const ushort* __restrict__ xl, const ushort* __restrict__ xr,
    const int* __restrict__ head, const int* __restrict__ nxt,
    const int* __restrict__ eisrc,
    const float* __restrict__ a, const float* __restrict__ b,
    const float* __restrict__ gam, const float* __restrict__ bet,
    ushort* __restrict__ hout) {
  constexpr int GROUP = FOUT / 8;   // 16 / 8 / 4
  constexpr int GPB = 256 / GROUP;
  int gid = blockIdx.x * GPB + threadIdx.x / GROUP;
  int lane = threadIdx.x % GROUP;
  const uint4* xl4 = (const uint4*)xl;

  float xrf[8];
  cvt8(((const uint4*)xr)[gid * GROUP + lane], xrf);
  float av[8];
  {
    float4 a0 = ((const float4*)a)[lane * 2], a1 = ((const float4*)a)[lane * 2 + 1];
    av[0] = a0.x; av[1] = a0.y; av[2] = a0.z; av[3] = a0.w;
    av[4] = a1.x; av[5] = a1.y; av[6] = a1.z; av[7] = a1.w;
  }

  // self loop first: chain seed (p = 1, m = self score)
  float xs[8];
  cvt8(xl4[(size_t)gid * GROUP + lane], xs);
  float m = 0.f;
#pragma unroll
  for (int j = 0; j < 8; ++j) {
    float z = xs[j] + xrf[j];
    m = fmaf(fmaxf(z, 0.2f * z), av[j], m);
  }
#pragma unroll
  for (int wd = GROUP >> 1; wd >= 1; wd >>= 1) m += __shfl_xor(m, wd);
  float den = 1.f;
  float acc[8];
#pragma unroll
  for (int j = 0; j < 8; ++j) acc[j] = xs[j];

  // walk chain with 1-ahead pointer prefetch
  int i = head[gid];
  int nx = -1, s = 0;
  if (i >= 0) { nx = nxt[i]; s = eisrc[i]; }
  while (i >= 0) {
    int i2 = nx, s2 = 0, nx2 = -1;
    if (i2 >= 0) { nx2 = nxt[i2]; s2 = eisrc[i2]; }
    uint4 v = xl4[(size_t)s * GROUP + lane];
    float x0[8];
    cvt8(v, x0);
    float sc = 0.f;
#pragma unroll
    for (int j = 0; j < 8; ++j) {
      float z = x0[j] + xrf[j];
      sc = fmaf(fmaxf(z, 0.2f * z), av[j], sc);
    }
#pragma unroll
    for (int wd = GROUP >> 1; wd >= 1; wd >>= 1) sc += __shfl_xor(sc, wd);
    float m2 = fmaxf(m, sc);
    float scale = __expf(m - m2);
    float p = __expf(sc - m2);
    den = fmaf(den, scale, p);
#pragma unroll
    for (int j = 0; j < 8; ++j) acc[j] = fmaf(acc[j], scale, p * x0[j]);
    m = m2;
    i = i2; s = s2; nx = nx2;
  }

  float inv = 1.f / den;
  float4 b0 = ((const float4*)b)[lane * 2], b1 = ((const float4*)b)[lane * 2 + 1];
  float4 g0 = ((const float4*)gam)[lane * 2], g1 = ((const float4*)gam)[lane * 2 + 1];
  float4 e0 = ((const float4*)bet)[lane * 2], e1 = ((const float4*)bet)[lane * 2 + 1];
  float bb[8] = {b0.x, b0.y, b0.z, b0.w, b1.x, b1.y, b1.z, b1.w};
  float gg[8] = {g0.x, g0.y, g0.z, g0.w, g1.x, g1.y, g1.z, g1.w};
  float ee[8] = {e0.x, e0.y, e0.z, e0.w, e1.x, e1.y, e1.z, e1.w};
  float o[8];
#pragma unroll
  for (int j = 0; j < 8; ++j)
    o[j] = fmaxf(acc[j] * inv + bb[j], 0.f) * (gg[j] * BNS) + ee[j];
  uint4 pv;
  pv.x = pack_bf2(o[0], o[1]); pv.y = pack_bf2(o[2], o[3]);
  pv.z = pack_bf2(o[4], o[5]); pv.w = pack_bf2(o[6], o[7]);
  ((uint4*)hout)[gid * GROUP + lane] = pv;
}

// ================= standalone pool (layer 3) =================

template <int FOUT>
__global__ __launch_bounds__(64) void pool_kernel(const ushort* __restrict__ h,
                                                  const int* __restrict__ goff,
                                                  float* __restrict__ pooled,
                                                  int colbase, int colbase2) {
  int g = blockIdx.x;
  int t = threadIdx.x;
  constexpr int PAIRS = FOUT / 2;
  if (t >= PAIRS) return;
  float a0 = 0.f, a1 = 0.f;
  int b0 = goff[g], b1 = goff[g + 1];
  const uint* h32 = (const uint*)h;
  for (int n = b0; n < b1; ++n) {
    uint v = h32[(size_t)n * PAIRS + t];
    a0 += lo_bf(v);
    a1 += hi_bf(v);
  }
  pooled[g * 256 + colbase + 2 * t] = a0;
  pooled[g * 256 + colbase + 2 * t + 1] = a1;
  if (colbase2 >= 0) {
    pooled[g * 256 + colbase2 + 2 * t] = a0;
    pooled[g * 256 + colbase2 + 2 * t + 1] = a1;
  }
}

// ================= MLP head + outputs =================

__global__ __launch_bounds__(128) void mlp_kernel(
    const float* __restrict__ pooled, const float* __restrict__ W1,
    const float* __restrict__ b1, const float* __restrict__ g5,
    const float* __restrict__ be5, const float* __restrict__ W2,
    const float* __restrict__ b2, float* __restrict__ out) {
  __shared__ float p[256];
  __shared__ float hid[128];
  __shared__ float lg[16];
  int g = blockIdx.x, t = threadIdx.x;
  p[t] = pooled[g * 256 + t];
  p[t + 128] = pooled[g * 256 + 128 + t];
  __syncthreads();
  float acc = b1[t];
  for (int k = 0; k < 256; ++k) acc = fmaf(p[k], W1[k * 128 + t], acc);
  acc = fmaxf(acc, 0.f) * (g5[t] * BNS) + be5[t];
  hid[t] = acc;
  __syncthreads();
  if (t < 16) {
    float l = b2[t];
    for (int k = 0; k < 128; ++k) l = fmaf(hid[k], W2[k * 16 + t], l);
    lg[t] = l;
  }
  __syncthreads();
  if (t < 16) {
    float l = lg[t];
    float m = lg[0];
    for (int k = 1; k < 16; ++k) m = fmaxf(m, lg[k]);
    float se = 0.f;
    for (int k = 0; k < 16; ++k) se += __expf(lg[k] - m);
    out[g * 16 + t] = 1.f / (1.f + __expf(-l));       // sigmoid
    out[NG * 16 + g * 16 + t] = l - m - __logf(se);   // log_softmax
  }
}

// ================= launch =================

extern "C" void kernel_launch(void* const* d_in, const int* in_sizes, int n_in,
                              void* d_out, int out_size, void* d_ws, size_t ws_size,
                              hipStream_t stream) {
  const float* x = (const float*)d_in[0];
  const int* ei = (const int*)d_in[1];
  const int* batch = (const int*)d_in[2];
  const float* Wl1 = (const float*)d_in[4];
  const float* Wr1 = (const float*)d_in[5];
  const float* a1 = (const float*)d_in[6];
  const float* b1 = (const float*)d_in[7];
  const float* g1 = (const float*)d_in[8];
  const float* be1 = (const float*)d_in[9];
  const float* Wl2 = (const float*)d_in[10];
  const float* Wr2 = (const float*)d_in[11];
  const float* a2 = (const float*)d_in[12];
  const float* b2 = (const float*)d_in[13];
  const float* g2 = (const float*)d_in[14];
  const float* be2 = (const float*)d_in[15];
  const float* Wl3 = (const float*)d_in[16];
  const float* Wr3 = (const float*)d_in[17];
  const float* a3 = (const float*)d_in[18];
  const float* b3 = (const float*)d_in[19];
  const float* g3 = (const float*)d_in[20];
  const float* be3 = (const float*)d_in[21];
  // layer 4 (d_in[22..27]) is dead in the reference (h4 = h3) — skipped.
  const float* lin1_W = (const float*)d_in[28];
  const float* lin1_b = (const float*)d_in[29];
  const float* g5 = (const float*)d_in[30];
  const float* be5 = (const float*)d_in[31];
  const float* lin2_W = (const float*)d_in[32];
  const float* lin2_b = (const float*)d_in[33];
  float* out = (float*)d_out;

  // workspace carve (16B-aligned chunks)
  char* w = (char*)d_ws;
  ushort* xl = (ushort*)w;  w += (size_t)NN * 128 * 2;  // 16 MB
  ushort* xr = (ushort*)w;  w += (size_t)NN * 128 * 2;  // 16 MB
  ushort* h  = (ushort*)w;  w += (size_t)NN * 128 * 2;  // 16 MB
  ushort* P1l = (ushort*)w; w += 65536;
  ushort* P1r = (ushort*)w; w += 65536;
  ushort* P2l = (ushort*)w; w += 65536;
  ushort* P2r = (ushort*)w; w += 65536;
  ushort* P3l = (ushort*)w; w += 65536;
  ushort* P3r = (ushort*)w; w += 65536;
  int* head = (int*)w;      w += (size_t)NN * 4;        // 256 KB
  int* nxt = (int*)w;       w += (size_t)EE * 4;        // 4 MB
  int* goff = (int*)w;      w += (size_t)(NG + 4) * 4;
  float* pooled = (float*)w; w += (size_t)NG * 256 * 4;

  hipMemsetAsync(head, 0xFF, (size_t)NN * 4, stream);  // head = -1

  // link | pack | gbound
  k_pre<<<PRE_B, 256, 0, stream>>>(ei, head, nxt, Wl1, Wr1, Wl2, Wr2,
                                   Wl3, Wr3, P1l, P1r, P2l, P2r, P3l, P3r,
                                   batch, goff);

  // ---- layer 1: 128 -> 128 (GEMM reads f32 x directly)
  k_gemm1f<<<512, 256, 0, stream>>>(x, P1l, P1r, xl, xr);
  edge_kernel<128><<<NN / 16, 256, 0, stream>>>(xl, xr, head, nxt, ei,
                                                a1, b1, g1, be1, h);

  // ---- layer 2: 128 -> 64 (pool1 overlapped)
  k_pool1_gemm2<<<POOL_B + 512, 256, 0, stream>>>(h, goff, pooled, P2l, P2r,
                                                  xl, xr);
  edge_kernel<64><<<NN / 32, 256, 0, stream>>>(xl, xr, head, nxt, ei,
                                               a2, b2, g2, be2, h);

  // ---- layer 3: 64 -> 32 (pool2 overlapped)
  k_pool2_gemm3<<<POOL_B + 256, 256, 0, stream>>>(h, goff, pooled, P3l, P3r,
                                                  xl, xr);
  edge_kernel<32><<<NN / 64, 256, 0, stream>>>(xl, xr, head, nxt, ei,
                                               a3, b3, g3, be3, h);

  pool_kernel<32><<<NG, 64, 0, stream>>>(h, goff, pooled, 192, 224);
  mlp_kernel<<<NG, 128, 0, stream>>>(pooled, lin1_W, lin1_b, g5, be5, lin2_W,
                                     lin2_b, out);
}

// Round 7
// 353.151 us; speedup vs baseline: 1.0973x; 1.0973x over previous
//
#include <hip/hip_runtime.h>
#include <hip/hip_bf16.h>
#include <math.h>

#define NN 65536
#define EE 1048576
#define NG 512

// k_pre block split: link | gemm1 | gbound
#define LINK_B 1024       // EE/4/256 exactly
#define GEMM1_B 512
#define GB_B   3
#define PRE_B  (LINK_B + GEMM1_B + GB_B)
#define POOL_B 512

typedef __attribute__((ext_vector_type(8))) short bf16x8;
typedef __attribute__((ext_vector_type(4))) float f32x4;

__device__ __constant__ const float BNS = 0.9999950000374997f; // 1/sqrt(1+1e-5)

// ---------------- bf16 helpers ----------------
__device__ inline float lo_bf(uint u) { union { uint i; float f; } v; v.i = u << 16; return v.f; }
__device__ inline float hi_bf(uint u) { union { uint i; float f; } v; v.i = u & 0xFFFF0000u; return v.f; }
__device__ inline uint f2bf(float f) {
  union { float f; uint i; } v; v.f = f;
  uint r = v.i + 0x7FFFu + ((v.i >> 16) & 1u);  // RTNE
  return r >> 16;
}
__device__ inline uint pack_bf2(float a, float b) { return f2bf(a) | (f2bf(b) << 16); }
__device__ inline void cvt8(uint4 v, float* o) {
  o[0] = lo_bf(v.x); o[1] = hi_bf(v.x); o[2] = lo_bf(v.y); o[3] = hi_bf(v.y);
  o[4] = lo_bf(v.z); o[5] = hi_bf(v.z); o[6] = lo_bf(v.w); o[7] = hi_bf(v.w);
}

// ================= device bodies =================

// 4 sub-chains per dst: head4[d*4 + (e&3)]. rec[e] = {src, next} (one 8B load
// per hop on the walk). nxt/rec stores are contiguous; only the atomicExch is
// random (1MB head4, L2-resident).
__device__ void dev_link(int lb, const int* __restrict__ ei,
                         int* __restrict__ head4, int2* __restrict__ rec) {
  int i0 = (lb * 256 + threadIdx.x) * 4;
  int4 s4 = *(const int4*)(ei + i0);
  int4 d4 = *(const int4*)(ei + EE + i0);
  int o0 = atomicExch(&head4[d4.x * 4 + 0], i0 + 0);
  int o1 = atomicExch(&head4[d4.y * 4 + 1], i0 + 1);
  int o2 = atomicExch(&head4[d4.z * 4 + 2], i0 + 2);
  int o3 = atomicExch(&head4[d4.w * 4 + 3], i0 + 3);
  int4 r01; r01.x = s4.x; r01.y = o0; r01.z = s4.y; r01.w = o1;
  int4 r23; r23.x = s4.z; r23.y = o2; r23.z = s4.w; r23.w = o3;
  *(int4*)(rec + i0) = r01;
  *(int4*)(rec + i0 + 2) = r23;
}

__device__ void dev_gbound(int lb, const int* __restrict__ batch,
                           int* __restrict__ goff) {
  int g = lb * 256 + threadIdx.x;
  if (g > NG) return;
  int lo = 0, hi = NN;
  while (lo < hi) {
    int mid = (lo + hi) >> 1;
    if (batch[mid] < g) lo = mid + 1; else hi = mid;
  }
  goff[g] = lo;
}

// GEMM tile body; W fragments loaded directly from f32 weights (L2-cached,
// ~64KB/block one-time). Input either f32 (layer 1) or bf16.
template <int FIN, int FOUT, int TILES, bool F32IN>
__device__ void dev_gemm(int lb, const void* __restrict__ xin,
                         const float* __restrict__ Wl,
                         const float* __restrict__ Wr,
                         ushort* __restrict__ xl, ushort* __restrict__ xr) {
  constexpr int KS = FIN / 32;
  constexpr int NF = FOUT / 16;
  constexpr int FW = (NF < 4) ? NF : 4;
  constexpr int CFW = NF / FW;
  constexpr int NW = 4 / FW;
  const int w = threadIdx.x >> 6, lane = threadIdx.x & 63;
  const int fseg = w % FW, ng = w / FW;
  const int l15 = lane & 15, lhi = lane >> 4;

  bf16x8 wfl[CFW][KS], wfr[CFW][KS];
#pragma unroll
  for (int c = 0; c < CFW; ++c)
#pragma unroll
    for (int t = 0; t < KS; ++t) {
      int f = (fseg * CFW + c) * 16 + l15;
      int k0 = t * 32 + lhi * 8;
      uint4 ul, ur;
      ul.x = pack_bf2(Wl[(k0 + 0) * FOUT + f], Wl[(k0 + 1) * FOUT + f]);
      ul.y = pack_bf2(Wl[(k0 + 2) * FOUT + f], Wl[(k0 + 3) * FOUT + f]);
      ul.z = pack_bf2(Wl[(k0 + 4) * FOUT + f], Wl[(k0 + 5) * FOUT + f]);
      ul.w = pack_bf2(Wl[(k0 + 6) * FOUT + f], Wl[(k0 + 7) * FOUT + f]);
      ur.x = pack_bf2(Wr[(k0 + 0) * FOUT + f], Wr[(k0 + 1) * FOUT + f]);
      ur.y = pack_bf2(Wr[(k0 + 2) * FOUT + f], Wr[(k0 + 3) * FOUT + f]);
      ur.z = pack_bf2(Wr[(k0 + 4) * FOUT + f], Wr[(k0 + 5) * FOUT + f]);
      ur.w = pack_bf2(Wr[(k0 + 6) * FOUT + f], Wr[(k0 + 7) * FOUT + f]);
      wfl[c][t] = *(bf16x8*)&ul;
      wfr[c][t] = *(bf16x8*)&ur;
    }

  size_t tile0 = ((size_t)lb * NW + ng) * TILES;
  for (int it = 0; it < TILES; ++it) {
    int mb = (int)(tile0 + it) * 16;
    bf16x8 bx[KS];
    if (F32IN) {
      const float* xrow = (const float*)xin + (size_t)(mb + l15) * FIN;
#pragma unroll
      for (int t = 0; t < KS; ++t) {
        float4 a0 = *(const float4*)(xrow + t * 32 + lhi * 8);
        float4 a1 = *(const float4*)(xrow + t * 32 + lhi * 8 + 4);
        uint4 u;
        u.x = pack_bf2(a0.x, a0.y); u.y = pack_bf2(a0.z, a0.w);
        u.z = pack_bf2(a1.x, a1.y); u.w = pack_bf2(a1.z, a1.w);
        bx[t] = *(bf16x8*)&u;
      }
    } else {
      const bf16x8* xrow = (const bf16x8*)((const ushort*)xin + (size_t)(mb + l15) * FIN);
#pragma unroll
      for (int t = 0; t < KS; ++t) bx[t] = xrow[t * 4 + lhi];
    }
    f32x4 accl[CFW], accr[CFW];
#pragma unroll
    for (int c = 0; c < CFW; ++c) {
      accl[c] = (f32x4){0.f, 0.f, 0.f, 0.f};
      accr[c] = (f32x4){0.f, 0.f, 0.f, 0.f};
    }
#pragma unroll
    for (int t = 0; t < KS; ++t)
#pragma unroll
      for (int c = 0; c < CFW; ++c) {
        accl[c] = __builtin_amdgcn_mfma_f32_16x16x32_bf16(wfl[c][t], bx[t], accl[c], 0, 0, 0);
        accr[c] = __builtin_amdgcn_mfma_f32_16x16x32_bf16(wfr[c][t], bx[t], accr[c], 0, 0, 0);
      }
#pragma unroll
    for (int c = 0; c < CFW; ++c) {
      int f0 = (fseg * CFW + c) * 16 + lhi * 4;
      size_t o = (size_t)(mb + l15) * FOUT + f0;
      uint2 vl; vl.x = pack_bf2(accl[c][0], accl[c][1]); vl.y = pack_bf2(accl[c][2], accl[c][3]);
      *(uint2*)(xl + o) = vl;
      uint2 vr; vr.x = pack_bf2(accr[c][0], accr[c][1]); vr.y = pack_bf2(accr[c][2], accr[c][3]);
      *(uint2*)(xr + o) = vr;
    }
  }
}

template <int FOUT>
__device__ void dev_pool(int g, const ushort* __restrict__ h,
                         const int* __restrict__ goff,
                         float* __restrict__ pooled, int colbase) {
  int t = threadIdx.x;
  constexpr int PAIRS = FOUT / 2;
  if (t >= PAIRS) return;
  float a0 = 0.f, a1 = 0.f;
  int b0 = goff[g], b1 = goff[g + 1];
  const uint* h32 = (const uint*)h;
  for (int n = b0; n < b1; ++n) {
    uint v = h32[(size_t)n * PAIRS + t];
    a0 += lo_bf(v);
    a1 += hi_bf(v);
  }
  pooled[g * 256 + colbase + 2 * t] = a0;
  pooled[g * 256 + colbase + 2 * t + 1] = a1;
}

// ================= fused kernels =================

__global__ __launch_bounds__(256) void k_pre(
    const int* __restrict__ ei, int* __restrict__ head4, int2* __restrict__ rec,
    const float* __restrict__ x,
    const float* __restrict__ Wl1, const float* __restrict__ Wr1,
    ushort* __restrict__ xl, ushort* __restrict__ xr,
    const int* __restrict__ batch, int* __restrict__ goff) {
  int b = blockIdx.x;
  if (b < LINK_B) dev_link(b, ei, head4, rec);
  else if (b < LINK_B + GEMM1_B)
    dev_gemm<128, 128, 8, true>(b - LINK_B, x, Wl1, Wr1, xl, xr);
  else dev_gbound(b - LINK_B - GEMM1_B, batch, goff);
}

__global__ __launch_bounds__(256) void k_pool1_gemm2(
    const ushort* __restrict__ h, const int* __restrict__ goff,
    float* __restrict__ pooled, const float* __restrict__ Wl2,
    const float* __restrict__ Wr2, ushort* __restrict__ xl,
    ushort* __restrict__ xr) {
  int b = blockIdx.x;
  if (b < POOL_B) dev_pool<128>(b, h, goff, pooled, 0);
  else dev_gemm<128, 64, 8, false>(b - POOL_B, h, Wl2, Wr2, xl, xr);
}

__global__ __launch_bounds__(256) void k_pool2_gemm3(
    const ushort* __restrict__ h, const int* __restrict__ goff,
    float* __restrict__ pooled, const float* __restrict__ Wl3,
    const float* __restrict__ Wr3, ushort* __restrict__ xl,
    ushort* __restrict__ xr) {
  int b = blockIdx.x;
  if (b < POOL_B) dev_pool<64>(b, h, goff, pooled, 128);
  else dev_gemm<64, 32, 8, false>(b - POOL_B, h, Wl3, Wr3, xl, xr);
}

// ================= edge aggregation: 4-chain walk, online softmax ============

template <int FOUT>
__global__ __launch_bounds__(256) void edge_kernel(
    const ushort* __restrict__ xl, const ushort* __restrict__ xr,
    const int* __restrict__ head4, const int2* __restrict__ rec,
    const float* __restrict__ a, const float* __restrict__ b,
    const float* __restrict__ gam, const float* __restrict__ bet,
    ushort* __restrict__ hout) {
  constexpr int GROUP = FOUT / 8;   // 16 / 8 / 4
  constexpr int GPB = 256 / GROUP;
  int gid = blockIdx.x * GPB + threadIdx.x / GROUP;
  int lane = threadIdx.x % GROUP;
  const uint4* xl4 = (const uint4*)xl;

  float xrf[8];
  cvt8(((const uint4*)xr)[gid * GROUP + lane], xrf);
  float av[8];
  {
    float4 a0 = ((const float4*)a)[lane * 2], a1 = ((const float4*)a)[lane * 2 + 1];
    av[0] = a0.x; av[1] = a0.y; av[2] = a0.z; av[3] = a0.w;
    av[4] = a1.x; av[5] = a1.y; av[6] = a1.z; av[7] = a1.w;
  }

  // self loop seeds the state (p = 1, m = self score)
  float xs[8];
  cvt8(xl4[(size_t)gid * GROUP + lane], xs);
  float m = 0.f;
#pragma unroll
  for (int j = 0; j < 8; ++j) {
    float z = xs[j] + xrf[j];
    m = fmaf(fmaxf(z, 0.2f * z), av[j], m);
  }
#pragma unroll
  for (int wd = GROUP >> 1; wd >= 1; wd >>= 1) m += __shfl_xor(m, wd);
  float den = 1.f;
  float acc[8];
#pragma unroll
  for (int j = 0; j < 8; ++j) acc[j] = xs[j];

  // 4 independent chains walked in lockstep (4 gathers + 4 rec loads in flight)
  int4 hh = ((const int4*)head4)[gid];
  int cur[4] = {hh.x, hh.y, hh.z, hh.w};
  int2 rc[4];
#pragma unroll
  for (int c = 0; c < 4; ++c)
    rc[c] = (cur[c] >= 0) ? rec[cur[c]] : make_int2(0, -1);

  while ((cur[0] >= 0) | (cur[1] >= 0) | (cur[2] >= 0) | (cur[3] >= 0)) {
    uint4 v[4];
#pragma unroll
    for (int c = 0; c < 4; ++c)
      if (cur[c] >= 0) v[c] = xl4[(size_t)rc[c].x * GROUP + lane];
    int2 rn[4];
#pragma unroll
    for (int c = 0; c < 4; ++c)
      rn[c] = (cur[c] >= 0 && rc[c].y >= 0) ? rec[rc[c].y] : make_int2(0, -1);
#pragma unroll
    for (int c = 0; c < 4; ++c) {
      if (cur[c] >= 0) {
        float xf[8];
        cvt8(v[c], xf);
        float sc = 0.f;
#pragma unroll
        for (int j = 0; j < 8; ++j) {
          float z = xf[j] + xrf[j];
          sc = fmaf(fmaxf(z, 0.2f * z), av[j], sc);
        }
#pragma unroll
        for (int wd = GROUP >> 1; wd >= 1; wd >>= 1) sc += __shfl_xor(sc, wd);
        float m2 = fmaxf(m, sc);
        float scale = __expf(m - m2);
        float p = __expf(sc - m2);
        den = fmaf(den, scale, p);
#pragma unroll
        for (int j = 0; j < 8; ++j) acc[j] = fmaf(acc[j], scale, p * xf[j]);
        m = m2;
      }
    }
#pragma unroll
    for (int c = 0; c < 4; ++c) {
      cur[c] = (cur[c] >= 0) ? rc[c].y : -1;
      rc[c] = rn[c];
    }
  }

  float inv = 1.f / den;
  float4 b0 = ((const float4*)b)[lane * 2], b1 = ((const float4*)b)[lane * 2 + 1];
  float4 g0 = ((const float4*)gam)[lane * 2], g1 = ((const float4*)gam)[lane * 2 + 1];
  float4 e0 = ((const float4*)bet)[lane * 2], e1 = ((const float4*)bet)[lane * 2 + 1];
  float bb[8] = {b0.x, b0.y, b0.z, b0.w, b1.x, b1.y, b1.z, b1.w};
  float gg[8] = {g0.x, g0.y, g0.z, g0.w, g1.x, g1.y, g1.z, g1.w};
  float ee[8] = {e0.x, e0.y, e0.z, e0.w, e1.x, e1.y, e1.z, e1.w};
  float o[8];
#pragma unroll
  for (int j = 0; j < 8; ++j)
    o[j] = fmaxf(acc[j] * inv + bb[j], 0.f) * (gg[j] * BNS) + ee[j];
  uint4 pv;
  pv.x = pack_bf2(o[0], o[1]); pv.y = pack_bf2(o[2], o[3]);
  pv.z = pack_bf2(o[4], o[5]); pv.w = pack_bf2(o[6], o[7]);
  ((uint4*)hout)[gid * GROUP + lane] = pv;
}

// ================= MLP head (pool3/pool4 fused in) =================

__global__ __launch_bounds__(128) void mlp_kernel(
    const ushort* __restrict__ h3, const int* __restrict__ goff,
    const float* __restrict__ pooled, const float* __restrict__ W1,
    const float* __restrict__ b1, const float* __restrict__ g5,
    const float* __restrict__ be5, const float* __restrict__ W2,
    const float* __restrict__ b2, float* __restrict__ out) {
  __shared__ float p[256];
  __shared__ float ps[8][16][2];
  __shared__ float hid[128];
  __shared__ float lg[16];
  int g = blockIdx.x, t = threadIdx.x;
  int n0 = goff[g], n1 = goff[g + 1];
  p[t] = pooled[g * 256 + t];
  if (t < 64) p[128 + t] = pooled[g * 256 + 128 + t];
  // pool3: 8 node-strides x 16 pair-threads
  {
    int sub = t >> 4, pi = t & 15;
    float a0 = 0.f, a1 = 0.f;
    const uint* h32 = (const uint*)h3;
    for (int n = n0 + sub; n < n1; n += 8) {
      uint v = h32[(size_t)n * 16 + pi];
      a0 += lo_bf(v);
      a1 += hi_bf(v);
    }
    ps[sub][pi][0] = a0;
    ps[sub][pi][1] = a1;
  }
  __syncthreads();
  if (t < 16) {
    float s0 = 0.f, s1 = 0.f;
#pragma unroll
    for (int s = 0; s < 8; ++s) { s0 += ps[s][t][0]; s1 += ps[s][t][1]; }
    p[192 + 2 * t] = s0; p[193 + 2 * t] = s1;   // p3
    p[224 + 2 * t] = s0; p[225 + 2 * t] = s1;   // p4 (= p3, reference bug)
  }
  __syncthreads();
  float acc = b1[t];
  for (int k = 0; k < 256; ++k) acc = fmaf(p[k], W1[k * 128 + t], acc);
  acc = fmaxf(acc, 0.f) * (g5[t] * BNS) + be5[t];
  hid[t] = acc;
  __syncthreads();
  if (t < 16) {
    float l = b2[t];
    for (int k = 0; k < 128; ++k) l = fmaf(hid[k], W2[k * 16 + t], l);
    lg[t] = l;
  }
  __syncthreads();
  if (t < 16) {
    float l = lg[t];
    float m = lg[0];
    for (int k = 1; k < 16; ++k) m = fmaxf(m, lg[k]);
    float se = 0.f;
    for (int k = 0; k < 16; ++k) se += __expf(lg[k] - m);
    out[g * 16 + t] = 1.f / (1.f + __expf(-l));       // sigmoid
    out[NG * 16 + g * 16 + t] = l - m - __logf(se);   // log_softmax
  }
}

// ================= launch =================

extern "C" void kernel_launch(void* const* d_in, const int* in_sizes, int n_in,
                              void* d_out, int out_size, void* d_ws, size_t ws_size,
                              hipStream_t stream) {
  const float* x = (const float*)d_in[0];
  const int* ei = (const int*)d_in[1];
  const int* batch = (const int*)d_in[2];
  const float* Wl1 = (const float*)d_in[4];
  const float* Wr1 = (const float*)d_in[5];
  const float* a1 = (const float*)d_in[6];
  const float* b1 = (const float*)d_in[7];
  const float* g1 = (const float*)d_in[8];
  const float* be1 = (const float*)d_in[9];
  const float* Wl2 = (const float*)d_in[10];
  const float* Wr2 = (const float*)d_in[11];
  const float* a2 = (const float*)d_in[12];
  const float* b2 = (const float*)d_in[13];
  const float* g2 = (const float*)d_in[14];
  const float* be2 = (const float*)d_in[15];
  const float* Wl3 = (const float*)d_in[16];
  const float* Wr3 = (const float*)d_in[17];
  const float* a3 = (const float*)d_in[18];
  const float* b3 = (const float*)d_in[19];
  const float* g3 = (const float*)d_in[20];
  const float* be3 = (const float*)d_in[21];
  // layer 4 (d_in[22..27]) is dead in the reference (h4 = h3) — skipped.
  const float* lin1_W = (const float*)d_in[28];
  const float* lin1_b = (const float*)d_in[29];
  const float* g5 = (const float*)d_in[30];
  const float* be5 = (const float*)d_in[31];
  const float* lin2_W = (const float*)d_in[32];
  const float* lin2_b = (const float*)d_in[33];
  float* out = (float*)d_out;

  // workspace carve (16B-aligned chunks)
  char* w = (char*)d_ws;
  ushort* xl = (ushort*)w;  w += (size_t)NN * 128 * 2;  // 16 MB
  ushort* xr = (ushort*)w;  w += (size_t)NN * 128 * 2;  // 16 MB
  ushort* h  = (ushort*)w;  w += (size_t)NN * 128 * 2;  // 16 MB
  int* head4 = (int*)w;     w += (size_t)NN * 4 * 4;    // 1 MB
  int2* rec = (int2*)w;     w += (size_t)EE * 8;        // 8 MB
  int* goff = (int*)w;      w += (size_t)(NG + 4) * 4;
  float* pooled = (float*)w; w += (size_t)NG * 256 * 4;

  hipMemsetAsync(head4, 0xFF, (size_t)NN * 4 * 4, stream);  // heads = -1

  // link | gemm1(f32 in, direct W) | gbound
  k_pre<<<PRE_B, 256, 0, stream>>>(ei, head4, rec, x, Wl1, Wr1, xl, xr,
                                   batch, goff);
  edge_kernel<128><<<NN / 16, 256, 0, stream>>>(xl, xr, head4, rec,
                                                a1, b1, g1, be1, h);

  // pool1 | gemm layer2
  k_pool1_gemm2<<<POOL_B + 512, 256, 0, stream>>>(h, goff, pooled, Wl2, Wr2,
                                                  xl, xr);
  edge_kernel<64><<<NN / 32, 256, 0, stream>>>(xl, xr, head4, rec,
                                               a2, b2, g2, be2, h);

  // pool2 | gemm layer3
  k_pool2_gemm3<<<POOL_B + 256, 256, 0, stream>>>(h, goff, pooled, Wl3, Wr3,
                                                  xl, xr);
  edge_kernel<32><<<NN / 64, 256, 0, stream>>>(xl, xr, head4, rec,
                                               a3, b3, g3, be3, h);

  // MLP head (pool3/p4 fused)
  mlp_kernel<<<NG, 128, 0, stream>>>(h, goff, pooled, lin1_W, lin1_b, g5, be5,
                                     lin2_W, lin2_b, out);
}

// Round 8
// 276.962 us; speedup vs baseline: 1.3992x; 1.2751x over previous
//
#include <hip/hip_runtime.h>
#include <hip/hip_bf16.h>
#include <math.h>

#define NN 65536
#define EE 1048576
#define NG 512

// fused splits
#define PH1A_B 256
#define GB_B   3
#define K1_B   (PH1A_B + GB_B)
#define PH1B_B 256
#define GEMM1_B 512
#define K2_B   (PH1B_B + GEMM1_B)
#define POOL_B 512

typedef __attribute__((ext_vector_type(8))) short bf16x8;
typedef __attribute__((ext_vector_type(4))) float f32x4;

__device__ __constant__ const float BNS = 0.9999950000374997f; // 1/sqrt(1+1e-5)

// ---------------- bf16 helpers ----------------
__device__ inline float lo_bf(uint u) { union { uint i; float f; } v; v.i = u << 16; return v.f; }
__device__ inline float hi_bf(uint u) { union { uint i; float f; } v; v.i = u & 0xFFFF0000u; return v.f; }
__device__ inline uint f2bf(float f) {
  union { float f; uint i; } v; v.f = f;
  uint r = v.i + 0x7FFFu + ((v.i >> 16) & 1u);  // RTNE
  return r >> 16;
}
__device__ inline uint pack_bf2(float a, float b) { return f2bf(a) | (f2bf(b) << 16); }
__device__ inline void cvt8(uint4 v, float* o) {
  o[0] = lo_bf(v.x); o[1] = hi_bf(v.x); o[2] = lo_bf(v.y); o[3] = hi_bf(v.y);
  o[4] = lo_bf(v.z); o[5] = hi_bf(v.z); o[6] = lo_bf(v.w); o[7] = hi_bf(v.w);
}

// ================= bucket-sort phase 1A: per-(block,bucket) counts =========

__device__ void dev_ph1a(int b, const int* __restrict__ ei,
                         int* __restrict__ ph1cnt) {
  __shared__ int lcnt[256];
  int t = threadIdx.x;
  lcnt[t] = 0;
  __syncthreads();
#pragma unroll
  for (int it = 0; it < 16; ++it) {
    int d = ei[EE + b * 4096 + it * 256 + t];
    atomicAdd(&lcnt[d >> 8], 1);
  }
  __syncthreads();
  ph1cnt[t * 256 + b] = lcnt[t];   // bucket-major for the scan
}

__device__ void dev_gbound(int lb, const int* __restrict__ batch,
                           int* __restrict__ goff) {
  int g = lb * 256 + threadIdx.x;
  if (g > NG) return;
  int lo = 0, hi = NN;
  while (lo < hi) {
    int mid = (lo + hi) >> 1;
    if (batch[mid] < g) lo = mid + 1; else hi = mid;
  }
  goff[g] = lo;
}

__global__ __launch_bounds__(256) void k_ph1a_gbound(
    const int* __restrict__ ei, int* __restrict__ ph1cnt,
    const int* __restrict__ batch, int* __restrict__ goff) {
  int b = blockIdx.x;
  if (b < PH1A_B) dev_ph1a(b, ei, ph1cnt);
  else dev_gbound(b - PH1A_B, batch, goff);
}

// ================= scans (plain exclusive, 65536 elems) =================

__global__ __launch_bounds__(256) void scan1_kernel(const int* __restrict__ cnt,
                                                    int* __restrict__ bsum) {
  __shared__ int ws[4];
  int b = blockIdx.x, t = threadIdx.x;
  int4 v = ((const int4*)(cnt + b * 1024))[t];
  int s = v.x + v.y + v.z + v.w;
#pragma unroll
  for (int d = 1; d < 64; d <<= 1) s += __shfl_xor(s, d);
  if ((t & 63) == 0) ws[t >> 6] = s;
  __syncthreads();
  if (t == 0) bsum[b] = ws[0] + ws[1] + ws[2] + ws[3];
}

__global__ __launch_bounds__(64) void scan2_kernel(const int* __restrict__ bsum,
                                                   int* __restrict__ boff) {
  int t = threadIdx.x;
  int v = bsum[t];
  int s = v;
#pragma unroll
  for (int d = 1; d < 64; d <<= 1) {
    int u = __shfl_up(s, d);
    if (t >= d) s += u;
  }
  boff[t] = s - v;
}

__global__ __launch_bounds__(256) void scan3_kernel(const int* __restrict__ cnt,
                                                    const int* __restrict__ boff,
                                                    int* __restrict__ off) {
  __shared__ int wsum[4];
  int b = blockIdx.x, t = threadIdx.x;
  int base = b * 1024;
  int4 v = ((const int4*)(cnt + base))[t];
  int s = v.x + v.y + v.z + v.w;
  int inc = s;
#pragma unroll
  for (int d = 1; d < 64; d <<= 1) {
    int u = __shfl_up(inc, d);
    if ((t & 63) >= d) inc += u;
  }
  int wave = t >> 6;
  if ((t & 63) == 63) wsum[wave] = inc;
  __syncthreads();
  int wadd = 0;
  for (int wv = 0; wv < wave; ++wv) wadd += wsum[wv];
  int ex = inc - s + wadd + boff[b];
  int4 o;
  o.x = ex; o.y = ex + v.x; o.z = o.y + v.y; o.w = o.z + v.z;
  ((int4*)(off + base))[t] = o;
}

// ================= phase 1B: bucket-scatter (LDS cursors only) =============

__device__ void dev_ph1b(int b, const int* __restrict__ ei,
                         const int* __restrict__ ph1off,
                         uint* __restrict__ ebuf) {
  __shared__ int lcur[256];
  int t = threadIdx.x;
  lcur[t] = ph1off[t * 256 + b];
  __syncthreads();
#pragma unroll
  for (int it = 0; it < 16; ++it) {
    int e = b * 4096 + it * 256 + t;
    int s = ei[e];
    int d = ei[EE + e];
    int pos = atomicAdd(&lcur[d >> 8], 1);
    ebuf[pos] = (uint)s | ((uint)(d & 255) << 16);
  }
}

// GEMM tile body; W fragments loaded directly from f32 weights.
template <int FIN, int FOUT, int TILES, bool F32IN>
__device__ void dev_gemm(int lb, const void* __restrict__ xin,
                         const float* __restrict__ Wl,
                         const float* __restrict__ Wr,
                         ushort* __restrict__ xl, ushort* __restrict__ xr) {
  constexpr int KS = FIN / 32;
  constexpr int NF = FOUT / 16;
  constexpr int FW = (NF < 4) ? NF : 4;
  constexpr int CFW = NF / FW;
  constexpr int NW = 4 / FW;
  const int w = threadIdx.x >> 6, lane = threadIdx.x & 63;
  const int fseg = w % FW, ng = w / FW;
  const int l15 = lane & 15, lhi = lane >> 4;

  bf16x8 wfl[CFW][KS], wfr[CFW][KS];
#pragma unroll
  for (int c = 0; c < CFW; ++c)
#pragma unroll
    for (int t = 0; t < KS; ++t) {
      int f = (fseg * CFW + c) * 16 + l15;
      int k0 = t * 32 + lhi * 8;
      uint4 ul, ur;
      ul.x = pack_bf2(Wl[(k0 + 0) * FOUT + f], Wl[(k0 + 1) * FOUT + f]);
      ul.y = pack_bf2(Wl[(k0 + 2) * FOUT + f], Wl[(k0 + 3) * FOUT + f]);
      ul.z = pack_bf2(Wl[(k0 + 4) * FOUT + f], Wl[(k0 + 5) * FOUT + f]);
      ul.w = pack_bf2(Wl[(k0 + 6) * FOUT + f], Wl[(k0 + 7) * FOUT + f]);
      ur.x = pack_bf2(Wr[(k0 + 0) * FOUT + f], Wr[(k0 + 1) * FOUT + f]);
      ur.y = pack_bf2(Wr[(k0 + 2) * FOUT + f], Wr[(k0 + 3) * FOUT + f]);
      ur.z = pack_bf2(Wr[(k0 + 4) * FOUT + f], Wr[(k0 + 5) * FOUT + f]);
      ur.w = pack_bf2(Wr[(k0 + 6) * FOUT + f], Wr[(k0 + 7) * FOUT + f]);
      wfl[c][t] = *(bf16x8*)&ul;
      wfr[c][t] = *(bf16x8*)&ur;
    }

  size_t tile0 = ((size_t)lb * NW + ng) * TILES;
  for (int it = 0; it < TILES; ++it) {
    int mb = (int)(tile0 + it) * 16;
    bf16x8 bx[KS];
    if (F32IN) {
      const float* xrow = (const float*)xin + (size_t)(mb + l15) * FIN;
#pragma unroll
      for (int t = 0; t < KS; ++t) {
        float4 a0 = *(const float4*)(xrow + t * 32 + lhi * 8);
        float4 a1 = *(const float4*)(xrow + t * 32 + lhi * 8 + 4);
        uint4 u;
        u.x = pack_bf2(a0.x, a0.y); u.y = pack_bf2(a0.z, a0.w);
        u.z = pack_bf2(a1.x, a1.y); u.w = pack_bf2(a1.z, a1.w);
        bx[t] = *(bf16x8*)&u;
      }
    } else {
      const bf16x8* xrow = (const bf16x8*)((const ushort*)xin + (size_t)(mb + l15) * FIN);
#pragma unroll
      for (int t = 0; t < KS; ++t) bx[t] = xrow[t * 4 + lhi];
    }
    f32x4 accl[CFW], accr[CFW];
#pragma unroll
    for (int c = 0; c < CFW; ++c) {
      accl[c] = (f32x4){0.f, 0.f, 0.f, 0.f};
      accr[c] = (f32x4){0.f, 0.f, 0.f, 0.f};
    }
#pragma unroll
    for (int t = 0; t < KS; ++t)
#pragma unroll
      for (int c = 0; c < CFW; ++c) {
        accl[c] = __builtin_amdgcn_mfma_f32_16x16x32_bf16(wfl[c][t], bx[t], accl[c], 0, 0, 0);
        accr[c] = __builtin_amdgcn_mfma_f32_16x16x32_bf16(wfr[c][t], bx[t], accr[c], 0, 0, 0);
      }
#pragma unroll
    for (int c = 0; c < CFW; ++c) {
      int f0 = (fseg * CFW + c) * 16 + lhi * 4;
      size_t o = (size_t)(mb + l15) * FOUT + f0;
      uint2 vl; vl.x = pack_bf2(accl[c][0], accl[c][1]); vl.y = pack_bf2(accl[c][2], accl[c][3]);
      *(uint2*)(xl + o) = vl;
      uint2 vr; vr.x = pack_bf2(accr[c][0], accr[c][1]); vr.y = pack_bf2(accr[c][2], accr[c][3]);
      *(uint2*)(xr + o) = vr;
    }
  }
}

__global__ __launch_bounds__(256) void k_ph1b_gemm1(
    const int* __restrict__ ei, const int* __restrict__ ph1off,
    uint* __restrict__ ebuf, const float* __restrict__ x,
    const float* __restrict__ Wl1, const float* __restrict__ Wr1,
    ushort* __restrict__ xl, ushort* __restrict__ xr) {
  int b = blockIdx.x;
  if (b < PH1B_B) dev_ph1b(b, ei, ph1off, ebuf);
  else dev_gemm<128, 128, 8, true>(b - PH1B_B, x, Wl1, Wr1, xl, xr);
}

// ================= phase 2: per-bucket counting sort → CSR =================

__global__ __launch_bounds__(256) void k_ph2(
    const int* __restrict__ ph1off, const uint* __restrict__ ebuf,
    int* __restrict__ csr_off, ushort* __restrict__ csr_src) {
  __shared__ int ccnt[256], coff[256], lcur[256], tmp[256];
  int k = blockIdx.x, t = threadIdx.x;
  int beg = ph1off[k * 256];
  int end = (k == 255) ? EE : ph1off[(k + 1) * 256];
  ccnt[t] = 0;
  lcur[t] = 0;
  __syncthreads();
  for (int e = beg + t; e < end; e += 256) {
    uint u = ebuf[e];
    atomicAdd(&ccnt[(u >> 16) & 255], 1);
  }
  __syncthreads();
  // exclusive scan of ccnt -> coff (Hillis-Steele)
  int s = ccnt[t];
  tmp[t] = s;
#pragma unroll
  for (int d = 1; d < 256; d <<= 1) {
    __syncthreads();
    int u = (t >= d) ? tmp[t - d] : 0;
    __syncthreads();
    tmp[t] += u;
  }
  __syncthreads();
  coff[t] = tmp[t] - s;
  csr_off[k * 256 + t] = beg + tmp[t] - s;
  if (k == 255 && t == 0) csr_off[NN] = EE;
  __syncthreads();
  for (int e = beg + t; e < end; e += 256) {
    uint u = ebuf[e];
    int j = (u >> 16) & 255;
    int pos = atomicAdd(&lcur[j], 1);
    csr_src[beg + coff[j] + pos] = (ushort)(u & 0xFFFFu);
  }
}

// ================= pools / gemms (layers 2,3) =================

template <int FOUT>
__device__ void dev_pool(int g, const ushort* __restrict__ h,
                         const int* __restrict__ goff,
                         float* __restrict__ pooled, int colbase) {
  int t = threadIdx.x;
  constexpr int PAIRS = FOUT / 2;
  if (t >= PAIRS) return;
  float a0 = 0.f, a1 = 0.f;
  int b0 = goff[g], b1 = goff[g + 1];
  const uint* h32 = (const uint*)h;
  for (int n = b0; n < b1; ++n) {
    uint v = h32[(size_t)n * PAIRS + t];
    a0 += lo_bf(v);
    a1 += hi_bf(v);
  }
  pooled[g * 256 + colbase + 2 * t] = a0;
  pooled[g * 256 + colbase + 2 * t + 1] = a1;
}

__global__ __launch_bounds__(256) void k_pool1_gemm2(
    const ushort* __restrict__ h, const int* __restrict__ goff,
    float* __restrict__ pooled, const float* __restrict__ Wl2,
    const float* __restrict__ Wr2, ushort* __restrict__ xl,
    ushort* __restrict__ xr) {
  int b = blockIdx.x;
  if (b < POOL_B) dev_pool<128>(b, h, goff, pooled, 0);
  else dev_gemm<128, 64, 8, false>(b - POOL_B, h, Wl2, Wr2, xl, xr);
}

__global__ __launch_bounds__(256) void k_pool2_gemm3(
    const ushort* __restrict__ h, const int* __restrict__ goff,
    float* __restrict__ pooled, const float* __restrict__ Wl3,
    const float* __restrict__ Wr3, ushort* __restrict__ xl,
    ushort* __restrict__ xr) {
  int b = blockIdx.x;
  if (b < POOL_B) dev_pool<64>(b, h, goff, pooled, 128);
  else dev_gemm<64, 32, 8, false>(b - POOL_B, h, Wl3, Wr3, xl, xr);
}

// ================= edge aggregation: CSR 4-wide, self-loop seeded ===========

template <int FOUT>
__global__ __launch_bounds__(256) void edge_kernel(
    const ushort* __restrict__ xl, const ushort* __restrict__ xr,
    const int* __restrict__ csr_off, const ushort* __restrict__ csr_src,
    const float* __restrict__ a, const float* __restrict__ b,
    const float* __restrict__ gam, const float* __restrict__ bet,
    ushort* __restrict__ hout) {
  constexpr int GROUP = FOUT / 8;   // 16 / 8 / 4
  constexpr int GPB = 256 / GROUP;
  int gid = blockIdx.x * GPB + threadIdx.x / GROUP;
  int lane = threadIdx.x % GROUP;
  const uint4* xl4 = (const uint4*)xl;

  float xrf[8];
  cvt8(((const uint4*)xr)[gid * GROUP + lane], xrf);
  float av[8];
  {
    float4 a0 = ((const float4*)a)[lane * 2], a1 = ((const float4*)a)[lane * 2 + 1];
    av[0] = a0.x; av[1] = a0.y; av[2] = a0.z; av[3] = a0.w;
    av[4] = a1.x; av[5] = a1.y; av[6] = a1.z; av[7] = a1.w;
  }

  // self loop seeds state (p = 1)
  float xs[8];
  cvt8(xl4[(size_t)gid * GROUP + lane], xs);
  float m = 0.f;
#pragma unroll
  for (int j = 0; j < 8; ++j) {
    float z = xs[j] + xrf[j];
    m = fmaf(fmaxf(z, 0.2f * z), av[j], m);
  }
#pragma unroll
  for (int wd = GROUP >> 1; wd >= 1; wd >>= 1) m += __shfl_xor(m, wd);
  float den = 1.f;
  float acc[8];
#pragma unroll
  for (int j = 0; j < 8; ++j) acc[j] = xs[j];

  int beg = csr_off[gid], end = csr_off[gid + 1];
  int i = beg;
  for (; i + 4 <= end; i += 4) {
    int s0 = csr_src[i], s1 = csr_src[i + 1];
    int s2 = csr_src[i + 2], s3 = csr_src[i + 3];
    uint4 v0 = xl4[(size_t)s0 * GROUP + lane];
    uint4 v1 = xl4[(size_t)s1 * GROUP + lane];
    uint4 v2 = xl4[(size_t)s2 * GROUP + lane];
    uint4 v3 = xl4[(size_t)s3 * GROUP + lane];
    float x0[8], x1[8], x2[8], x3[8];
    cvt8(v0, x0); cvt8(v1, x1); cvt8(v2, x2); cvt8(v3, x3);
    float sc0 = 0.f, sc1 = 0.f, sc2 = 0.f, sc3 = 0.f;
#pragma unroll
    for (int j = 0; j < 8; ++j) {
      float z0 = x0[j] + xrf[j];
      float z1 = x1[j] + xrf[j];
      float z2 = x2[j] + xrf[j];
      float z3 = x3[j] + xrf[j];
      sc0 = fmaf(fmaxf(z0, 0.2f * z0), av[j], sc0);
      sc1 = fmaf(fmaxf(z1, 0.2f * z1), av[j], sc1);
      sc2 = fmaf(fmaxf(z2, 0.2f * z2), av[j], sc2);
      sc3 = fmaf(fmaxf(z3, 0.2f * z3), av[j], sc3);
    }
#pragma unroll
    for (int wd = GROUP >> 1; wd >= 1; wd >>= 1) {
      sc0 += __shfl_xor(sc0, wd);
      sc1 += __shfl_xor(sc1, wd);
      sc2 += __shfl_xor(sc2, wd);
      sc3 += __shfl_xor(sc3, wd);
    }
    float m2 = fmaxf(m, fmaxf(fmaxf(sc0, sc1), fmaxf(sc2, sc3)));
    float scale = __expf(m - m2);
    float p0 = __expf(sc0 - m2), p1 = __expf(sc1 - m2);
    float p2 = __expf(sc2 - m2), p3 = __expf(sc3 - m2);
    den = den * scale + p0 + p1 + p2 + p3;
#pragma unroll
    for (int j = 0; j < 8; ++j)
      acc[j] = fmaf(acc[j], scale,
                    fmaf(p0, x0[j], fmaf(p1, x1[j], fmaf(p2, x2[j], p3 * x3[j]))));
    m = m2;
  }
  for (; i < end; ++i) {
    int s0 = csr_src[i];
    uint4 v0 = xl4[(size_t)s0 * GROUP + lane];
    float x0[8];
    cvt8(v0, x0);
    float sc0 = 0.f;
#pragma unroll
    for (int j = 0; j < 8; ++j) {
      float z0 = x0[j] + xrf[j];
      sc0 = fmaf(fmaxf(z0, 0.2f * z0), av[j], sc0);
    }
#pragma unroll
    for (int wd = GROUP >> 1; wd >= 1; wd >>= 1) sc0 += __shfl_xor(sc0, wd);
    float m2 = fmaxf(m, sc0);
    float scale = __expf(m - m2);
    float p0 = __expf(sc0 - m2);
    den = den * scale + p0;
#pragma unroll
    for (int j = 0; j < 8; ++j) acc[j] = fmaf(acc[j], scale, p0 * x0[j]);
    m = m2;
  }

  float inv = 1.f / den;
  float4 b0 = ((const float4*)b)[lane * 2], b1 = ((const float4*)b)[lane * 2 + 1];
  float4 g0 = ((const float4*)gam)[lane * 2], g1 = ((const float4*)gam)[lane * 2 + 1];
  float4 e0 = ((const float4*)bet)[lane * 2], e1 = ((const float4*)bet)[lane * 2 + 1];
  float bb[8] = {b0.x, b0.y, b0.z, b0.w, b1.x, b1.y, b1.z, b1.w};
  float gg[8] = {g0.x, g0.y, g0.z, g0.w, g1.x, g1.y, g1.z, g1.w};
  float ee[8] = {e0.x, e0.y, e0.z, e0.w, e1.x, e1.y, e1.z, e1.w};
  float o[8];
#pragma unroll
  for (int j = 0; j < 8; ++j)
    o[j] = fmaxf(acc[j] * inv + bb[j], 0.f) * (gg[j] * BNS) + ee[j];
  uint4 pv;
  pv.x = pack_bf2(o[0], o[1]); pv.y = pack_bf2(o[2], o[3]);
  pv.z = pack_bf2(o[4], o[5]); pv.w = pack_bf2(o[6], o[7]);
  ((uint4*)hout)[gid * GROUP + lane] = pv;
}

// ================= MLP head (pool3/pool4 fused in) =================

__global__ __launch_bounds__(128) void mlp_kernel(
    const ushort* __restrict__ h3, const int* __restrict__ goff,
    const float* __restrict__ pooled, const float* __restrict__ W1,
    const float* __restrict__ b1, const float* __restrict__ g5,
    const float* __restrict__ be5, const float* __restrict__ W2,
    const float* __restrict__ b2, float* __restrict__ out) {
  __shared__ float p[256];
  __shared__ float ps[8][16][2];
  __shared__ float hid[128];
  __shared__ float lg[16];
  int g = blockIdx.x, t = threadIdx.x;
  int n0 = goff[g], n1 = goff[g + 1];
  p[t] = pooled[g * 256 + t];
  if (t < 64) p[128 + t] = pooled[g * 256 + 128 + t];
  {
    int sub = t >> 4, pi = t & 15;
    float a0 = 0.f, a1 = 0.f;
    const uint* h32 = (const uint*)h3;
    for (int n = n0 + sub; n < n1; n += 8) {
      uint v = h32[(size_t)n * 16 + pi];
      a0 += lo_bf(v);
      a1 += hi_bf(v);
    }
    ps[sub][pi][0] = a0;
    ps[sub][pi][1] = a1;
  }
  __syncthreads();
  if (t < 16) {
    float s0 = 0.f, s1 = 0.f;
#pragma unroll
    for (int s = 0; s < 8; ++s) { s0 += ps[s][t][0]; s1 += ps[s][t][1]; }
    p[192 + 2 * t] = s0; p[193 + 2 * t] = s1;   // p3
    p[224 + 2 * t] = s0; p[225 + 2 * t] = s1;   // p4 (= p3, reference bug)
  }
  __syncthreads();
  float acc = b1[t];
  for (int k = 0; k < 256; ++k) acc = fmaf(p[k], W1[k * 128 + t], acc);
  acc = fmaxf(acc, 0.f) * (g5[t] * BNS) + be5[t];
  hid[t] = acc;
  __syncthreads();
  if (t < 16) {
    float l = b2[t];
    for (int k = 0; k < 128; ++k) l = fmaf(hid[k], W2[k * 16 + t], l);
    lg[t] = l;
  }
  __syncthreads();
  if (t < 16) {
    float l = lg[t];
    float m = lg[0];
    for (int k = 1; k < 16; ++k) m = fmaxf(m, lg[k]);
    float se = 0.f;
    for (int k = 0; k < 16; ++k) se += __expf(lg[k] - m);
    out[g * 16 + t] = 1.f / (1.f + __expf(-l));       // sigmoid
    out[NG * 16 + g * 16 + t] = l - m - __logf(se);   // log_softmax
  }
}

// ================= launch =================

extern "C" void kernel_launch(void* const* d_in, const int* in_sizes, int n_in,
                              void* d_out, int out_size, void* d_ws, size_t ws_size,
                              hipStream_t stream) {
  const float* x = (const float*)d_in[0];
  const int* ei = (const int*)d_in[1];
  const int* batch = (const int*)d_in[2];
  const float* Wl1 = (const float*)d_in[4];
  const float* Wr1 = (const float*)d_in[5];
  const float* a1 = (const float*)d_in[6];
  const float* b1 = (const float*)d_in[7];
  const float* g1 = (const float*)d_in[8];
  const float* be1 = (const float*)d_in[9];
  const float* Wl2 = (const float*)d_in[10];
  const float* Wr2 = (const float*)d_in[11];
  const float* a2 = (const float*)d_in[12];
  const float* b2 = (const float*)d_in[13];
  const float* g2 = (const float*)d_in[14];
  const float* be2 = (const float*)d_in[15];
  const float* Wl3 = (const float*)d_in[16];
  const float* Wr3 = (const float*)d_in[17];
  const float* a3 = (const float*)d_in[18];
  const float* b3 = (const float*)d_in[19];
  const float* g3 = (const float*)d_in[20];
  const float* be3 = (const float*)d_in[21];
  // layer 4 (d_in[22..27]) is dead in the reference (h4 = h3) — skipped.
  const float* lin1_W = (const float*)d_in[28];
  const float* lin1_b = (const float*)d_in[29];
  const float* g5 = (const float*)d_in[30];
  const float* be5 = (const float*)d_in[31];
  const float* lin2_W = (const float*)d_in[32];
  const float* lin2_b = (const float*)d_in[33];
  float* out = (float*)d_out;

  // workspace carve (16B-aligned chunks)
  char* w = (char*)d_ws;
  ushort* xl = (ushort*)w;   w += (size_t)NN * 128 * 2;  // 16 MB
  ushort* xr = (ushort*)w;   w += (size_t)NN * 128 * 2;  // 16 MB
  ushort* h  = (ushort*)w;   w += (size_t)NN * 128 * 2;  // 16 MB
  uint* ebuf = (uint*)w;     w += (size_t)EE * 4;        // 4 MB
  int* ph1cnt = (int*)w;     w += (size_t)65536 * 4;     // 256 KB
  int* ph1off = (int*)w;     w += (size_t)(65536 + 16) * 4;
  int* csr_off = (int*)w;    w += (size_t)(NN + 4) * 4;
  ushort* csr_src = (ushort*)w; w += (size_t)(EE + 8) * 2;
  int* bsum = (int*)w;       w += 64 * 4;
  int* boff = (int*)w;       w += 64 * 4;
  int* goff = (int*)w;       w += (size_t)(NG + 4) * 4;
  float* pooled = (float*)w; w += (size_t)NG * 256 * 4;

  // bucket counts | graph bounds
  k_ph1a_gbound<<<K1_B, 256, 0, stream>>>(ei, ph1cnt, batch, goff);
  scan1_kernel<<<64, 256, 0, stream>>>(ph1cnt, bsum);
  scan2_kernel<<<1, 64, 0, stream>>>(bsum, boff);
  scan3_kernel<<<64, 256, 0, stream>>>(ph1cnt, boff, ph1off);

  // bucket scatter | gemm layer1 (f32 in)
  k_ph1b_gemm1<<<K2_B, 256, 0, stream>>>(ei, ph1off, ebuf, x, Wl1, Wr1, xl, xr);
  k_ph2<<<256, 256, 0, stream>>>(ph1off, ebuf, csr_off, csr_src);

  edge_kernel<128><<<NN / 16, 256, 0, stream>>>(xl, xr, csr_off, csr_src,
                                                a1, b1, g1, be1, h);

  // pool1 | gemm layer2
  k_pool1_gemm2<<<POOL_B + 512, 256, 0, stream>>>(h, goff, pooled, Wl2, Wr2,
                                                  xl, xr);
  edge_kernel<64><<<NN / 32, 256, 0, stream>>>(xl, xr, csr_off, csr_src,
                                               a2, b2, g2, be2, h);

  // pool2 | gemm layer3
  k_pool2_gemm3<<<POOL_B + 256, 256, 0, stream>>>(h, goff, pooled, Wl3, Wr3,
                                                  xl, xr);
  edge_kernel<32><<<NN / 64, 256, 0, stream>>>(xl, xr, csr_off, csr_src,
                                               a3, b3, g3, be3, h);

  // MLP head (pool3/p4 fused)
  mlp_kernel<<<NG, 128, 0, stream>>>(h, goff, pooled, lin1_W, lin1_b, g5, be5,
                                     lin2_W, lin2_b, out);
}

// Round 9
// 266.350 us; speedup vs baseline: 1.4550x; 1.0398x over previous
//
#include <hip/hip_runtime.h>
#include <hip/hip_bf16.h>
#include <math.h>

#define NN 65536
#define EE 1048576
#define NG 512

// fused splits
#define PH1A_B 256
#define PACK_B 26
#define GB_B   3
#define K1_B   (PH1A_B + PACK_B + GB_B)
#define PH2_B  256
#define GEMM1_B 512
#define K2_B   (PH2_B + GEMM1_B)
#define POOL_B 512

typedef __attribute__((ext_vector_type(8))) short bf16x8;
typedef __attribute__((ext_vector_type(4))) float f32x4;

__device__ __constant__ const float BNS = 0.9999950000374997f; // 1/sqrt(1+1e-5)

// ---------------- bf16 helpers ----------------
__device__ inline float lo_bf(uint u) { union { uint i; float f; } v; v.i = u << 16; return v.f; }
__device__ inline float hi_bf(uint u) { union { uint i; float f; } v; v.i = u & 0xFFFF0000u; return v.f; }
__device__ inline uint f2bf(float f) {
  union { float f; uint i; } v; v.f = f;
  uint r = v.i + 0x7FFFu + ((v.i >> 16) & 1u);  // RTNE
  return r >> 16;
}
__device__ inline uint pack_bf2(float a, float b) { return f2bf(a) | (f2bf(b) << 16); }
__device__ inline void cvt8(uint4 v, float* o) {
  o[0] = lo_bf(v.x); o[1] = hi_bf(v.x); o[2] = lo_bf(v.y); o[3] = hi_bf(v.y);
  o[4] = lo_bf(v.z); o[5] = hi_bf(v.z); o[6] = lo_bf(v.w); o[7] = hi_bf(v.w);
}

// ================= phase 1A: per-(block,bucket) counts =================

__device__ void dev_ph1a(int b, const int* __restrict__ ei,
                         int* __restrict__ ph1cnt) {
  __shared__ int lcnt[256];
  int t = threadIdx.x;
  lcnt[t] = 0;
  __syncthreads();
#pragma unroll
  for (int it = 0; it < 16; ++it) {
    int d = ei[EE + b * 4096 + it * 256 + t];
    atomicAdd(&lcnt[d >> 8], 1);
  }
  __syncthreads();
  ph1cnt[t * 256 + b] = lcnt[t];   // bucket-major for the scan
}

// pack W [FIN x FOUT] f32 into MFMA A-fragment layout (bf16)
__device__ void dev_pack(int b,
    const float* __restrict__ Wl1, const float* __restrict__ Wr1,
    const float* __restrict__ Wl2, const float* __restrict__ Wr2,
    const float* __restrict__ Wl3, const float* __restrict__ Wr3,
    ushort* __restrict__ P1l, ushort* __restrict__ P1r,
    ushort* __restrict__ P2l, ushort* __restrict__ P2r,
    ushort* __restrict__ P3l, ushort* __restrict__ P3r) {
  const float* W; ushort* P; int FIN, FOUT, base;
  if (b < 8)       { W = Wl1; P = P1l; FIN = 128; FOUT = 128; base = b; }
  else if (b < 16) { W = Wr1; P = P1r; FIN = 128; FOUT = 128; base = b - 8; }
  else if (b < 20) { W = Wl2; P = P2l; FIN = 128; FOUT = 64;  base = b - 16; }
  else if (b < 24) { W = Wr2; P = P2r; FIN = 128; FOUT = 64;  base = b - 20; }
  else if (b < 25) { W = Wl3; P = P3l; FIN = 64;  FOUT = 32;  base = 0; }
  else             { W = Wr3; P = P3r; FIN = 64;  FOUT = 32;  base = 0; }
  int tid = base * 256 + threadIdx.x;
  int KS = FIN / 32, NF = FOUT / 16;
  if (tid >= NF * KS * 64) return;
  int lane = tid & 63, t = (tid >> 6) % KS, cf = (tid >> 6) / KS;
  int f = cf * 16 + (lane & 15);
  int k0 = t * 32 + (lane >> 4) * 8;
  uint4 v;
  v.x = pack_bf2(W[(k0 + 0) * FOUT + f], W[(k0 + 1) * FOUT + f]);
  v.y = pack_bf2(W[(k0 + 2) * FOUT + f], W[(k0 + 3) * FOUT + f]);
  v.z = pack_bf2(W[(k0 + 4) * FOUT + f], W[(k0 + 5) * FOUT + f]);
  v.w = pack_bf2(W[(k0 + 6) * FOUT + f], W[(k0 + 7) * FOUT + f]);
  ((uint4*)P)[tid] = v;
}

__device__ void dev_gbound(int lb, const int* __restrict__ batch,
                           int* __restrict__ goff) {
  int g = lb * 256 + threadIdx.x;
  if (g > NG) return;
  int lo = 0, hi = NN;
  while (lo < hi) {
    int mid = (lo + hi) >> 1;
    if (batch[mid] < g) lo = mid + 1; else hi = mid;
  }
  goff[g] = lo;
}

__global__ __launch_bounds__(256) void k_ph1a_pack_gbound(
    const int* __restrict__ ei, int* __restrict__ ph1cnt,
    const float* __restrict__ Wl1, const float* __restrict__ Wr1,
    const float* __restrict__ Wl2, const float* __restrict__ Wr2,
    const float* __restrict__ Wl3, const float* __restrict__ Wr3,
    ushort* __restrict__ P1l, ushort* __restrict__ P1r,
    ushort* __restrict__ P2l, ushort* __restrict__ P2r,
    ushort* __restrict__ P3l, ushort* __restrict__ P3r,
    const int* __restrict__ batch, int* __restrict__ goff) {
  int b = blockIdx.x;
  if (b < PH1A_B) dev_ph1a(b, ei, ph1cnt);
  else if (b < PH1A_B + PACK_B)
    dev_pack(b - PH1A_B, Wl1, Wr1, Wl2, Wr2, Wl3, Wr3,
             P1l, P1r, P2l, P2r, P3l, P3r);
  else dev_gbound(b - PH1A_B - PACK_B, batch, goff);
}

// ================= scans =================

__global__ __launch_bounds__(256) void scan1_kernel(const int* __restrict__ cnt,
                                                    int* __restrict__ bsum) {
  __shared__ int ws[4];
  int b = blockIdx.x, t = threadIdx.x;
  int4 v = ((const int4*)(cnt + b * 1024))[t];
  int s = v.x + v.y + v.z + v.w;
#pragma unroll
  for (int d = 1; d < 64; d <<= 1) s += __shfl_xor(s, d);
  if ((t & 63) == 0) ws[t >> 6] = s;
  __syncthreads();
  if (t == 0) bsum[b] = ws[0] + ws[1] + ws[2] + ws[3];
}

__global__ __launch_bounds__(64) void scan2_kernel(const int* __restrict__ bsum,
                                                   int* __restrict__ boff) {
  int t = threadIdx.x;
  int v = bsum[t];
  int s = v;
#pragma unroll
  for (int d = 1; d < 64; d <<= 1) {
    int u = __shfl_up(s, d);
    if (t >= d) s += u;
  }
  boff[t] = s - v;
}

__global__ __launch_bounds__(256) void scan3_kernel(const int* __restrict__ cnt,
                                                    const int* __restrict__ boff,
                                                    int* __restrict__ off) {
  __shared__ int wsum[4];
  int b = blockIdx.x, t = threadIdx.x;
  int base = b * 1024;
  int4 v = ((const int4*)(cnt + base))[t];
  int s = v.x + v.y + v.z + v.w;
  int inc = s;
#pragma unroll
  for (int d = 1; d < 64; d <<= 1) {
    int u = __shfl_up(inc, d);
    if ((t & 63) >= d) inc += u;
  }
  int wave = t >> 6;
  if ((t & 63) == 63) wsum[wave] = inc;
  __syncthreads();
  int wadd = 0;
  for (int wv = 0; wv < wave; ++wv) wadd += wsum[wv];
  int ex = inc - s + wadd + boff[b];
  int4 o;
  o.x = ex; o.y = ex + v.x; o.z = o.y + v.y; o.w = o.z + v.z;
  ((int4*)(off + base))[t] = o;
}

// ================= phase 1B: bucket-scatter (LDS cursors only) =============

__global__ __launch_bounds__(256) void k_ph1b(const int* __restrict__ ei,
                                              const int* __restrict__ ph1off,
                                              uint* __restrict__ ebuf) {
  __shared__ int lcur[256];
  int b = blockIdx.x, t = threadIdx.x;
  lcur[t] = ph1off[t * 256 + b];
  __syncthreads();
#pragma unroll
  for (int it = 0; it < 16; ++it) {
    int e = b * 4096 + it * 256 + t;
    int s = ei[e];
    int d = ei[EE + e];
    int pos = atomicAdd(&lcur[d >> 8], 1);
    ebuf[pos] = (uint)s | ((uint)(d & 255) << 16);
  }
}

// ================= GEMM (packed W fragments) =================

template <int FIN, int FOUT, int TILES, bool F32IN>
__device__ void dev_gemm(int lb, const void* __restrict__ xin,
                         const ushort* __restrict__ Wlp,
                         const ushort* __restrict__ Wrp,
                         ushort* __restrict__ xl, ushort* __restrict__ xr) {
  constexpr int KS = FIN / 32;
  constexpr int NF = FOUT / 16;
  constexpr int FW = (NF < 4) ? NF : 4;
  constexpr int CFW = NF / FW;
  constexpr int NW = 4 / FW;
  const int w = threadIdx.x >> 6, lane = threadIdx.x & 63;
  const int fseg = w % FW, ng = w / FW;
  const int l15 = lane & 15, lhi = lane >> 4;

  bf16x8 wfl[CFW][KS], wfr[CFW][KS];
#pragma unroll
  for (int c = 0; c < CFW; ++c)
#pragma unroll
    for (int t = 0; t < KS; ++t) {
      int idx = ((fseg * CFW + c) * KS + t) * 64 + lane;
      wfl[c][t] = ((const bf16x8*)Wlp)[idx];
      wfr[c][t] = ((const bf16x8*)Wrp)[idx];
    }

  size_t tile0 = ((size_t)lb * NW + ng) * TILES;
  for (int it = 0; it < TILES; ++it) {
    int mb = (int)(tile0 + it) * 16;
    bf16x8 bx[KS];
    if (F32IN) {
      const float* xrow = (const float*)xin + (size_t)(mb + l15) * FIN;
#pragma unroll
      for (int t = 0; t < KS; ++t) {
        float4 a0 = *(const float4*)(xrow + t * 32 + lhi * 8);
        float4 a1 = *(const float4*)(xrow + t * 32 + lhi * 8 + 4);
        uint4 u;
        u.x = pack_bf2(a0.x, a0.y); u.y = pack_bf2(a0.z, a0.w);
        u.z = pack_bf2(a1.x, a1.y); u.w = pack_bf2(a1.z, a1.w);
        bx[t] = *(bf16x8*)&u;
      }
    } else {
      const bf16x8* xrow = (const bf16x8*)((const ushort*)xin + (size_t)(mb + l15) * FIN);
#pragma unroll
      for (int t = 0; t < KS; ++t) bx[t] = xrow[t * 4 + lhi];
    }
    f32x4 accl[CFW], accr[CFW];
#pragma unroll
    for (int c = 0; c < CFW; ++c) {
      accl[c] = (f32x4){0.f, 0.f, 0.f, 0.f};
      accr[c] = (f32x4){0.f, 0.f, 0.f, 0.f};
    }
#pragma unroll
    for (int t = 0; t < KS; ++t)
#pragma unroll
      for (int c = 0; c < CFW; ++c) {
        accl[c] = __builtin_amdgcn_mfma_f32_16x16x32_bf16(wfl[c][t], bx[t], accl[c], 0, 0, 0);
        accr[c] = __builtin_amdgcn_mfma_f32_16x16x32_bf16(wfr[c][t], bx[t], accr[c], 0, 0, 0);
      }
#pragma unroll
    for (int c = 0; c < CFW; ++c) {
      int f0 = (fseg * CFW + c) * 16 + lhi * 4;
      size_t o = (size_t)(mb + l15) * FOUT + f0;
      uint2 vl; vl.x = pack_bf2(accl[c][0], accl[c][1]); vl.y = pack_bf2(accl[c][2], accl[c][3]);
      *(uint2*)(xl + o) = vl;
      uint2 vr; vr.x = pack_bf2(accr[c][0], accr[c][1]); vr.y = pack_bf2(accr[c][2], accr[c][3]);
      *(uint2*)(xr + o) = vr;
    }
  }
}

// ================= phase 2: per-bucket counting sort → CSR =================

__device__ void dev_ph2(int k, const int* __restrict__ ph1off,
                        const uint* __restrict__ ebuf,
                        int* __restrict__ csr_off, ushort* __restrict__ csr_src) {
  __shared__ int ccnt[256], coff[256], lcur[256], tmp[256];
  int t = threadIdx.x;
  int beg = ph1off[k * 256];
  int end = (k == 255) ? EE : ph1off[(k + 1) * 256];
  ccnt[t] = 0;
  lcur[t] = 0;
  __syncthreads();
  for (int e = beg + t; e < end; e += 256) {
    uint u = ebuf[e];
    atomicAdd(&ccnt[(u >> 16) & 255], 1);
  }
  __syncthreads();
  int s = ccnt[t];
  tmp[t] = s;
#pragma unroll
  for (int d = 1; d < 256; d <<= 1) {
    __syncthreads();
    int u = (t >= d) ? tmp[t - d] : 0;
    __syncthreads();
    tmp[t] += u;
  }
  __syncthreads();
  coff[t] = tmp[t] - s;
  csr_off[k * 256 + t] = beg + tmp[t] - s;
  if (k == 255 && t == 0) csr_off[NN] = EE;
  __syncthreads();
  for (int e = beg + t; e < end; e += 256) {
    uint u = ebuf[e];
    int j = (u >> 16) & 255;
    int pos = atomicAdd(&lcur[j], 1);
    csr_src[beg + coff[j] + pos] = (ushort)(u & 0xFFFFu);
  }
}

__global__ __launch_bounds__(256) void k_ph2_gemm1(
    const int* __restrict__ ph1off, const uint* __restrict__ ebuf,
    int* __restrict__ csr_off, ushort* __restrict__ csr_src,
    const float* __restrict__ x, const ushort* __restrict__ P1l,
    const ushort* __restrict__ P1r, ushort* __restrict__ xl,
    ushort* __restrict__ xr) {
  int b = blockIdx.x;
  if (b < PH2_B) dev_ph2(b, ph1off, ebuf, csr_off, csr_src);
  else dev_gemm<128, 128, 8, true>(b - PH2_B, x, P1l, P1r, xl, xr);
}

// ================= pools / gemms (layers 2,3) =================

template <int FOUT>
__device__ void dev_pool(int g, const ushort* __restrict__ h,
                         const int* __restrict__ goff,
                         float* __restrict__ pooled, int colbase) {
  int t = threadIdx.x;
  constexpr int PAIRS = FOUT / 2;
  if (t >= PAIRS) return;
  float a0 = 0.f, a1 = 0.f;
  int b0 = goff[g], b1 = goff[g + 1];
  const uint* h32 = (const uint*)h;
  for (int n = b0; n < b1; ++n) {
    uint v = h32[(size_t)n * PAIRS + t];
    a0 += lo_bf(v);
    a1 += hi_bf(v);
  }
  pooled[g * 256 + colbase + 2 * t] = a0;
  pooled[g * 256 + colbase + 2 * t + 1] = a1;
}

__global__ __launch_bounds__(256) void k_pool1_gemm2(
    const ushort* __restrict__ h, const int* __restrict__ goff,
    float* __restrict__ pooled, const ushort* __restrict__ P2l,
    const ushort* __restrict__ P2r, ushort* __restrict__ xl,
    ushort* __restrict__ xr) {
  int b = blockIdx.x;
  if (b < POOL_B) dev_pool<128>(b, h, goff, pooled, 0);
  else dev_gemm<128, 64, 8, false>(b - POOL_B, h, P2l, P2r, xl, xr);
}

__global__ __launch_bounds__(256) void k_pool2_gemm3(
    const ushort* __restrict__ h, const int* __restrict__ goff,
    float* __restrict__ pooled, const ushort* __restrict__ P3l,
    const ushort* __restrict__ P3r, ushort* __restrict__ xl,
    ushort* __restrict__ xr) {
  int b = blockIdx.x;
  if (b < POOL_B) dev_pool<64>(b, h, goff, pooled, 128);
  else dev_gemm<64, 32, 8, false>(b - POOL_B, h, P3l, P3r, xl, xr);
}

// ================= edge aggregation: CSR 4-wide, self-loop seeded ===========

template <int FOUT>
__global__ __launch_bounds__(256) void edge_kernel(
    const ushort* __restrict__ xl, const ushort* __restrict__ xr,
    const int* __restrict__ csr_off, const ushort* __restrict__ csr_src,
    const float* __restrict__ a, const float* __restrict__ b,
    const float* __restrict__ gam, const float* __restrict__ bet,
    ushort* __restrict__ hout) {
  constexpr int GROUP = FOUT / 8;   // 16 / 8 / 4
  constexpr int GPB = 256 / GROUP;
  int gid = blockIdx.x * GPB + threadIdx.x / GROUP;
  int lane = threadIdx.x % GROUP;
  const uint4* xl4 = (const uint4*)xl;

  float xrf[8];
  cvt8(((const uint4*)xr)[gid * GROUP + lane], xrf);
  float av[8];
  {
    float4 a0 = ((const float4*)a)[lane * 2], a1 = ((const float4*)a)[lane * 2 + 1];
    av[0] = a0.x; av[1] = a0.y; av[2] = a0.z; av[3] = a0.w;
    av[4] = a1.x; av[5] = a1.y; av[6] = a1.z; av[7] = a1.w;
  }

  // self loop seeds state (p = 1)
  float xs[8];
  cvt8(xl4[(size_t)gid * GROUP + lane], xs);
  float m = 0.f;
#pragma unroll
  for (int j = 0; j < 8; ++j) {
    float z = xs[j] + xrf[j];
    m = fmaf(fmaxf(z, 0.2f * z), av[j], m);
  }
#pragma unroll
  for (int wd = GROUP >> 1; wd >= 1; wd >>= 1) m += __shfl_xor(m, wd);
  float den = 1.f;
  float acc[8];
#pragma unroll
  for (int j = 0; j < 8; ++j) acc[j] = xs[j];

  int beg = csr_off[gid], end = csr_off[gid + 1];
  int i = beg;
  for (; i + 4 <= end; i += 4) {
    int s0 = csr_src[i], s1 = csr_src[i + 1];
    int s2 = csr_src[i + 2], s3 = csr_src[i + 3];
    uint4 v0 = xl4[(size_t)s0 * GROUP + lane];
    uint4 v1 = xl4[(size_t)s1 * GROUP + lane];
    uint4 v2 = xl4[(size_t)s2 * GROUP + lane];
    uint4 v3 = xl4[(size_t)s3 * GROUP + lane];
    float x0[8], x1[8], x2[8], x3[8];
    cvt8(v0, x0); cvt8(v1, x1); cvt8(v2, x2); cvt8(v3, x3);
    float sc0 = 0.f, sc1 = 0.f, sc2 = 0.f, sc3 = 0.f;
#pragma unroll
    for (int j = 0; j < 8; ++j) {
      float z0 = x0[j] + xrf[j];
      float z1 = x1[j] + xrf[j];
      float z2 = x2[j] + xrf[j];
      float z3 = x3[j] + xrf[j];
      sc0 = fmaf(fmaxf(z0, 0.2f * z0), av[j], sc0);
      sc1 = fmaf(fmaxf(z1, 0.2f * z1), av[j], sc1);
      sc2 = fmaf(fmaxf(z2, 0.2f * z2), av[j], sc2);
      sc3 = fmaf(fmaxf(z3, 0.2f * z3), av[j], sc3);
    }
#pragma unroll
    for (int wd = GROUP >> 1; wd >= 1; wd >>= 1) {
      sc0 += __shfl_xor(sc0, wd);
      sc1 += __shfl_xor(sc1, wd);
      sc2 += __shfl_xor(sc2, wd);
      sc3 += __shfl_xor(sc3, wd);
    }
    float m2 = fmaxf(m, fmaxf(fmaxf(sc0, sc1), fmaxf(sc2, sc3)));
    float scale = __expf(m - m2);
    float p0 = __expf(sc0 - m2), p1 = __expf(sc1 - m2);
    float p2 = __expf(sc2 - m2), p3 = __expf(sc3 - m2);
    den = den * scale + p0 + p1 + p2 + p3;
#pragma unroll
    for (int j = 0; j < 8; ++j)
      acc[j] = fmaf(acc[j], scale,
                    fmaf(p0, x0[j], fmaf(p1, x1[j], fmaf(p2, x2[j], p3 * x3[j]))));
    m = m2;
  }
  for (; i < end; ++i) {
    int s0 = csr_src[i];
    uint4 v0 = xl4[(size_t)s0 * GROUP + lane];
    float x0[8];
    cvt8(v0, x0);
    float sc0 = 0.f;
#pragma unroll
    for (int j = 0; j < 8; ++j) {
      float z0 = x0[j] + xrf[j];
      sc0 = fmaf(fmaxf(z0, 0.2f * z0), av[j], sc0);
    }
#pragma unroll
    for (int wd = GROUP >> 1; wd >= 1; wd >>= 1) sc0 += __shfl_xor(sc0, wd);
    float m2 = fmaxf(m, sc0);
    float scale = __expf(m - m2);
    float p0 = __expf(sc0 - m2);
    den = den * scale + p0;
#pragma unroll
    for (int j = 0; j < 8; ++j) acc[j] = fmaf(acc[j], scale, p0 * x0[j]);
    m = m2;
  }

  float inv = 1.f / den;
  float4 b0 = ((const float4*)b)[lane * 2], b1 = ((const float4*)b)[lane * 2 + 1];
  float4 g0 = ((const float4*)gam)[lane * 2], g1 = ((const float4*)gam)[lane * 2 + 1];
  float4 e0 = ((const float4*)bet)[lane * 2], e1 = ((const float4*)bet)[lane * 2 + 1];
  float bb[8] = {b0.x, b0.y, b0.z, b0.w, b1.x, b1.y, b1.z, b1.w};
  float gg[8] = {g0.x, g0.y, g0.z, g0.w, g1.x, g1.y, g1.z, g1.w};
  float ee[8] = {e0.x, e0.y, e0.z, e0.w, e1.x, e1.y, e1.z, e1.w};
  float o[8];
#pragma unroll
  for (int j = 0; j < 8; ++j)
    o[j] = fmaxf(acc[j] * inv + bb[j], 0.f) * (gg[j] * BNS) + ee[j];
  uint4 pv;
  pv.x = pack_bf2(o[0], o[1]); pv.y = pack_bf2(o[2], o[3]);
  pv.z = pack_bf2(o[4], o[5]); pv.w = pack_bf2(o[6], o[7]);
  ((uint4*)hout)[gid * GROUP + lane] = pv;
}

// ================= MLP head (pool3/pool4 fused in) =================

__global__ __launch_bounds__(128) void mlp_kernel(
    const ushort* __restrict__ h3, const int* __restrict__ goff,
    const float* __restrict__ pooled, const float* __restrict__ W1,
    const float* __restrict__ b1, const float* __restrict__ g5,
    const float* __restrict__ be5, const float* __restrict__ W2,
    const float* __restrict__ b2, float* __restrict__ out) {
  __shared__ float p[256];
  __shared__ float ps[8][16][2];
  __shared__ float hid[128];
  __shared__ float lg[16];
  int g = blockIdx.x, t = threadIdx.x;
  int n0 = goff[g], n1 = goff[g + 1];
  p[t] = pooled[g * 256 + t];
  if (t < 64) p[128 + t] = pooled[g * 256 + 128 + t];
  {
    int sub = t >> 4, pi = t & 15;
    float a0 = 0.f, a1 = 0.f;
    const uint* h32 = (const uint*)h3;
    for (int n = n0 + sub; n < n1; n += 8) {
      uint v = h32[(size_t)n * 16 + pi];
      a0 += lo_bf(v);
      a1 += hi_bf(v);
    }
    ps[sub][pi][0] = a0;
    ps[sub][pi][1] = a1;
  }
  __syncthreads();
  if (t < 16) {
    float s0 = 0.f, s1 = 0.f;
#pragma unroll
    for (int s = 0; s < 8; ++s) { s0 += ps[s][t][0]; s1 += ps[s][t][1]; }
    p[192 + 2 * t] = s0; p[193 + 2 * t] = s1;   // p3
    p[224 + 2 * t] = s0; p[225 + 2 * t] = s1;   // p4 (= p3, reference bug)
  }
  __syncthreads();
  float acc = b1[t];
  for (int k = 0; k < 256; ++k) acc = fmaf(p[k], W1[k * 128 + t], acc);
  acc = fmaxf(acc, 0.f) * (g5[t] * BNS) + be5[t];
  hid[t] = acc;
  __syncthreads();
  if (t < 16) {
    float l = b2[t];
    for (int k = 0; k < 128; ++k) l = fmaf(hid[k], W2[k * 16 + t], l);
    lg[t] = l;
  }
  __syncthreads();
  if (t < 16) {
    float l = lg[t];
    float m = lg[0];
    for (int k = 1; k < 16; ++k) m = fmaxf(m, lg[k]);
    float se = 0.f;
    for (int k = 0; k < 16; ++k) se += __expf(lg[k] - m);
    out[g * 16 + t] = 1.f / (1.f + __expf(-l));       // sigmoid
    out[NG * 16 + g * 16 + t] = l - m - __logf(se);   // log_softmax
  }
}

// ================= launch =================

extern "C" void kernel_launch(void* const* d_in, const int* in_sizes, int n_in,
                              void* d_out, int out_size, void* d_ws, size_t ws_size,
                              hipStream_t stream) {
  const float* x = (const float*)d_in[0];
  const int* ei = (const int*)d_in[1];
  const int* batch = (const int*)d_in[2];
  const float* Wl1 = (const float*)d_in[4];
  const float* Wr1 = (const float*)d_in[5];
  const float* a1 = (const float*)d_in[6];
  const float* b1 = (const float*)d_in[7];
  const float* g1 = (const float*)d_in[8];
  const float* be1 = (const float*)d_in[9];
  const float* Wl2 = (const float*)d_in[10];
  const float* Wr2 = (const float*)d_in[11];
  const float* a2 = (const float*)d_in[12];
  const float* b2 = (const float*)d_in[13];
  const float* g2 = (const float*)d_in[14];
  const float* be2 = (const float*)d_in[15];
  const float* Wl3 = (const float*)d_in[16];
  const float* Wr3 = (const float*)d_in[17];
  const float* a3 = (const float*)d_in[18];
  const float* b3 = (const float*)d_in[19];
  const float* g3 = (const float*)d_in[20];
  const float* be3 = (const float*)d_in[21];
  // layer 4 (d_in[22..27]) is dead in the reference (h4 = h3) — skipped.
  const float* lin1_W = (const float*)d_in[28];
  const float* lin1_b = (const float*)d_in[29];
  const float* g5 = (const float*)d_in[30];
  const float* be5 = (const float*)d_in[31];
  const float* lin2_W = (const float*)d_in[32];
  const float* lin2_b = (const float*)d_in[33];
  float* out = (float*)d_out;

  // workspace carve (16B-aligned chunks)
  char* w = (char*)d_ws;
  ushort* xl = (ushort*)w;   w += (size_t)NN * 128 * 2;  // 16 MB
  ushort* xr = (ushort*)w;   w += (size_t)NN * 128 * 2;  // 16 MB
  ushort* h  = (ushort*)w;   w += (size_t)NN * 128 * 2;  // 16 MB
  uint* ebuf = (uint*)w;     w += (size_t)EE * 4;        // 4 MB
  int* ph1cnt = (int*)w;     w += (size_t)65536 * 4;     // 256 KB
  int* ph1off = (int*)w;     w += (size_t)(65536 + 16) * 4;
  int* csr_off = (int*)w;    w += (size_t)(NN + 4) * 4;
  ushort* csr_src = (ushort*)w; w += (size_t)(EE + 8) * 2;
  ushort* P1l = (ushort*)w;  w += 65536;
  ushort* P1r = (ushort*)w;  w += 65536;
  ushort* P2l = (ushort*)w;  w += 65536;
  ushort* P2r = (ushort*)w;  w += 65536;
  ushort* P3l = (ushort*)w;  w += 65536;
  ushort* P3r = (ushort*)w;  w += 65536;
  int* bsum = (int*)w;       w += 64 * 4;
  int* boff = (int*)w;       w += 64 * 4;
  int* goff = (int*)w;       w += (size_t)(NG + 4) * 4;
  float* pooled = (float*)w; w += (size_t)NG * 256 * 4;

  // bucket counts | weight pack | graph bounds
  k_ph1a_pack_gbound<<<K1_B, 256, 0, stream>>>(ei, ph1cnt, Wl1, Wr1, Wl2, Wr2,
                                               Wl3, Wr3, P1l, P1r, P2l, P2r,
                                               P3l, P3r, batch, goff);
  scan1_kernel<<<64, 256, 0, stream>>>(ph1cnt, bsum);
  scan2_kernel<<<1, 64, 0, stream>>>(bsum, boff);
  scan3_kernel<<<64, 256, 0, stream>>>(ph1cnt, boff, ph1off);

  // bucket scatter
  k_ph1b<<<256, 256, 0, stream>>>(ei, ph1off, ebuf);

  // counting sort | gemm layer1 (f32 in, packed W)
  k_ph2_gemm1<<<K2_B, 256, 0, stream>>>(ph1off, ebuf, csr_off, csr_src,
                                        x, P1l, P1r, xl, xr);

  edge_kernel<128><<<NN / 16, 256, 0, stream>>>(xl, xr, csr_off, csr_src,
                                                a1, b1, g1, be1, h);

  // pool1 | gemm layer2
  k_pool1_gemm2<<<POOL_B + 512, 256, 0, stream>>>(h, goff, pooled, P2l, P2r,
                                                  xl, xr);
  edge_kernel<64><<<NN / 32, 256, 0, stream>>>(xl, xr, csr_off, csr_src,
                                               a2, b2, g2, be2, h);

  // pool2 | gemm layer3
  k_pool2_gemm3<<<POOL_B + 256, 256, 0, stream>>>(h, goff, pooled, P3l, P3r,
                                                  xl, xr);
  edge_kernel<32><<<NN / 64, 256, 0, stream>>>(xl, xr, csr_off, csr_src,
                                               a3, b3, g3, be3, h);

  // MLP head (pool3/p4 fused)
  mlp_kernel<<<NG, 128, 0, stream>>>(h, goff, pooled, lin1_W, lin1_b, g5, be5,
                                     lin2_W, lin2_b, out);
}